// Round 1
// baseline (3390.098 us; speedup 1.0000x reference)
//
#include <hip/hip_runtime.h>
#include <math.h>

static constexpr int BB = 2;
static constexpr int TT = 1024;
static constexpr int CC = 2048;
static constexpr int HH = 32;
static constexpr int KD = 64;
static constexpr int BT = BB * TT;

// ---------------- K1: h = tanh(xxx @ w1), one block per (b,t) row ----------------
__global__ void k_lora1(const float* __restrict__ x, const float* __restrict__ shift,
                        const float* __restrict__ maa_x, const float* __restrict__ w1,
                        float* __restrict__ h_out) {
    int row = blockIdx.x;            // 0..BT-1
    int b = row / TT, t = row % TT;
    __shared__ float xs[CC];
    const float* xr = x + (size_t)row * CC;
    const float* xp = (t == 0) ? (shift + (size_t)b * CC) : (xr - CC);
    for (int c = threadIdx.x; c < CC; c += blockDim.x) {
        float xv = xr[c];
        float dx = xp[c] - xv;
        xs[c] = xv + dx * maa_x[c];
    }
    __syncthreads();
    int j = threadIdx.x;
    if (j < 96) {
        float acc = 0.f;
        for (int c = 0; c < CC; ++c) acc += xs[c] * w1[c * 96 + j];
        h_out[(size_t)row * 96 + j] = tanhf(acc);
    }
}

// ---------------- K2: xq/xk/xv = x + dx*(maa + h_l @ w2_l), block per row ----------------
__global__ void k_mix(const float* __restrict__ x, const float* __restrict__ shift,
                      const float* __restrict__ h_in, const float* __restrict__ w2,
                      const float* __restrict__ maa_r, const float* __restrict__ maa_k,
                      const float* __restrict__ maa_v,
                      float* __restrict__ oq, float* __restrict__ ok, float* __restrict__ ov) {
    int row = blockIdx.x;
    int b = row / TT, t = row % TT;
    __shared__ float hs[96];
    if (threadIdx.x < 96) hs[threadIdx.x] = h_in[(size_t)row * 96 + threadIdx.x];
    __syncthreads();
    const float* xr = x + (size_t)row * CC;
    const float* xp = (t == 0) ? (shift + (size_t)b * CC) : (xr - CC);
    for (int c = threadIdx.x; c < CC; c += blockDim.x) {
        float xv = xr[c];
        float dx = xp[c] - xv;
        float m0 = 0.f, m1 = 0.f, m2 = 0.f;
        #pragma unroll
        for (int i = 0; i < 32; ++i) {
            m0 += hs[i]      * w2[(size_t)(i)      * CC + c];
            m1 += hs[32 + i] * w2[(size_t)(32 + i) * CC + c];
            m2 += hs[64 + i] * w2[(size_t)(64 + i) * CC + c];
        }
        size_t o = (size_t)row * CC + c;
        oq[o] = xv + dx * (maa_r[c] + m0);
        ok[o] = xv + dx * (maa_k[c] + m1);
        ov[o] = xv + dx * (maa_v[c] + m2);
    }
}

// ---------------- K3: tiled f32 GEMM  Y[M,N] = A[M,K] @ W[K,N] ----------------
__global__ __launch_bounds__(256) void k_gemm(const float* __restrict__ A,
                                              const float* __restrict__ W,
                                              float* __restrict__ Y,
                                              int M, int N, int K) {
    __shared__ float As[32][65];   // [k][m] transposed, padded (kills 32-way conflict)
    __shared__ float Bs[32][64];   // [k][n]
    int tid = threadIdx.x;
    int bm = blockIdx.y * 64, bn = blockIdx.x * 64;
    int tm = tid >> 4, tn = tid & 15;
    float acc[4][4] = {};
    for (int k0 = 0; k0 < K; k0 += 32) {
        {
            int col = tid & 31, r0 = tid >> 5;      // coalesced along K
            #pragma unroll
            for (int r = r0; r < 64; r += 8)
                As[col][r] = A[(size_t)(bm + r) * K + k0 + col];
        }
        {
            int col = tid & 63, r0 = tid >> 6;      // coalesced along N
            #pragma unroll
            for (int r = r0; r < 32; r += 4)
                Bs[r][col] = W[(size_t)(k0 + r) * N + bn + col];
        }
        __syncthreads();
        #pragma unroll
        for (int kk = 0; kk < 32; ++kk) {
            float a[4], bv[4];
            #pragma unroll
            for (int i = 0; i < 4; ++i) a[i] = As[kk][tm * 4 + i];
            #pragma unroll
            for (int j = 0; j < 4; ++j) bv[j] = Bs[kk][tn * 4 + j];
            #pragma unroll
            for (int i = 0; i < 4; ++i)
                #pragma unroll
                for (int j = 0; j < 4; ++j) acc[i][j] += a[i] * bv[j];
        }
        __syncthreads();
    }
    #pragma unroll
    for (int i = 0; i < 4; ++i)
        #pragma unroll
        for (int j = 0; j < 4; ++j)
            Y[(size_t)(bm + tm * 4 + i) * N + bn + tn * 4 + j] = acc[i][j];
}

// ---------------- K4: row LayerNorm over C (optionally in-place; no restrict!) ----------------
__global__ void k_ln(float* y, const float* xin, const float* g, const float* bb) {
    int row = blockIdx.x;
    const float* xr = xin + (size_t)row * CC;
    float s = 0.f, ss = 0.f;
    for (int c = threadIdx.x; c < CC; c += blockDim.x) {
        float v = xr[c]; s += v; ss += v * v;
    }
    #pragma unroll
    for (int o = 32; o > 0; o >>= 1) { s += __shfl_xor(s, o); ss += __shfl_xor(ss, o); }
    __shared__ float red[8];
    int wid = threadIdx.x >> 6;
    if ((threadIdx.x & 63) == 0) { red[wid] = s; red[wid + 4] = ss; }
    __syncthreads();
    s  = red[0] + red[1] + red[2] + red[3];
    ss = red[4] + red[5] + red[6] + red[7];
    float mu  = s * (1.0f / CC);
    float var = ss * (1.0f / CC) - mu * mu;
    float rsg = rsqrtf(var + 1e-5f);
    float* yr = y + (size_t)row * CC;
    for (int c = threadIdx.x; c < CC; c += blockDim.x)
        yr[c] = (xr[c] - mu) * rsg * g[c] + bb[c];
}

// ---------------- K5: RoPE in-place on q and k ----------------
__global__ void k_rope(float* q, float* k,
                       const float* __restrict__ cosb, const float* __restrict__ sinb) {
    int idx = blockIdx.x * blockDim.x + threadIdx.x;   // (b,t,h,d<32)
    int d = idx & 31;
    int h = (idx >> 5) & (HH - 1);
    int t = (idx >> 10) & (TT - 1);
    int b = idx >> 20;
    if (b >= BB) return;
    size_t base = ((size_t)(b * TT + t) * CC) + h * KD;
    float cv = cosb[t * 32 + d], sv = sinb[t * 32 + d];
    float q1 = q[base + d], q2 = q[base + d + 32];
    q[base + d]      = q1 * cv - q2 * sv;
    q[base + d + 32] = q1 * sv + q2 * cv;
    float k1 = k[base + d], k2 = k[base + d + 32];
    k[base + d]      = k1 * cv - k2 * sv;
    k[base + d + 32] = k1 * sv + k2 * cv;
}

// ---------------- K6: causal attention, one block per (b,h,t) ----------------
__global__ __launch_bounds__(256) void k_attn(const float* __restrict__ q,
                                              const float* __restrict__ k,
                                              const float* __restrict__ v,
                                              float* __restrict__ o) {
    int t = blockIdx.x, h = blockIdx.y, b = blockIdx.z;
    __shared__ float qs[KD];
    __shared__ float sc[TT];
    __shared__ float red[8];
    __shared__ float part[4][KD];
    int tid = threadIdx.x;
    size_t qbase = ((size_t)(b * TT + t) * CC) + h * KD;
    if (tid < KD) qs[tid] = q[qbase + tid] * 0.125f;   // 1/sqrt(64)
    __syncthreads();
    int ns = t + 1;
    float lmax = -1e30f;
    for (int s = tid; s < ns; s += 256) {
        const float* kr = k + ((size_t)(b * TT + s) * CC) + h * KD;
        float acc = 0.f;
        #pragma unroll
        for (int d = 0; d < KD; ++d) acc += qs[d] * kr[d];
        sc[s] = acc;
        lmax = fmaxf(lmax, acc);
    }
    #pragma unroll
    for (int o_ = 32; o_ > 0; o_ >>= 1) lmax = fmaxf(lmax, __shfl_xor(lmax, o_));
    if ((tid & 63) == 0) red[tid >> 6] = lmax;
    __syncthreads();
    float m = fmaxf(fmaxf(red[0], red[1]), fmaxf(red[2], red[3]));
    float lsum = 0.f;
    for (int s = tid; s < ns; s += 256) {
        float p = __expf(sc[s] - m);
        sc[s] = p;
        lsum += p;
    }
    #pragma unroll
    for (int o_ = 32; o_ > 0; o_ >>= 1) lsum += __shfl_xor(lsum, o_);
    __syncthreads();                      // sc fully written; red free for reuse
    if ((tid & 63) == 0) red[tid >> 6] = lsum;
    __syncthreads();
    float l = red[0] + red[1] + red[2] + red[3];
    float inv = 1.0f / l;
    int d = tid & 63, g = tid >> 6;
    float acc = 0.f;
    for (int s = g; s < ns; s += 4)
        acc += sc[s] * v[((size_t)(b * TT + s) * CC) + h * KD + d];
    part[g][d] = acc;
    __syncthreads();
    if (g == 0)
        o[qbase + d] = (part[0][d] + part[1][d] + part[2][d] + part[3][d]) * inv;
}

extern "C" void kernel_launch(void* const* d_in, const int* in_sizes, int n_in,
                              void* d_out, int out_size, void* d_ws, size_t ws_size,
                              hipStream_t stream) {
    const float* x     = (const float*)d_in[0];
    const float* shift = (const float*)d_in[1];
    const float* maa_x = (const float*)d_in[2];
    const float* maa_r = (const float*)d_in[3];
    const float* maa_k = (const float*)d_in[4];
    const float* maa_v = (const float*)d_in[5];
    const float* w1    = (const float*)d_in[6];
    const float* w2    = (const float*)d_in[7];
    const float* Wq    = (const float*)d_in[8];
    const float* Wk    = (const float*)d_in[9];
    const float* Wv    = (const float*)d_in[10];
    const float* Wo    = (const float*)d_in[11];
    const float* g_r   = (const float*)d_in[12];
    const float* b_r   = (const float*)d_in[13];
    const float* g_k   = (const float*)d_in[14];
    const float* b_k   = (const float*)d_in[15];
    const float* g_v   = (const float*)d_in[16];
    const float* b_v   = (const float*)d_in[17];
    const float* g_x   = (const float*)d_in[18];
    const float* b_x   = (const float*)d_in[19];
    const float* cosb  = (const float*)d_in[20];
    const float* sinb  = (const float*)d_in[21];

    float* ws = (float*)d_ws;
    const size_t NE = (size_t)BT * CC;       // 4M floats
    float* xq  = ws;
    float* xk  = ws + NE;
    float* xv  = ws + 2 * NE;
    float* qb  = ws + 3 * NE;
    float* kb  = ws + 4 * NE;
    float* vb  = ws + 5 * NE;
    float* hb  = ws + 6 * NE;                // BT*96 floats
    float* ob  = xq;                         // reuse (xq consumed by q GEMM)
    float* oln = xk;                         // reuse (xk consumed by k GEMM)
    float* out = (float*)d_out;

    k_lora1<<<BT, 128, 0, stream>>>(x, shift, maa_x, w1, hb);
    k_mix<<<BT, 256, 0, stream>>>(x, shift, hb, w2, maa_r, maa_k, maa_v, xq, xk, xv);

    dim3 gg(CC / 64, BT / 64);
    k_gemm<<<gg, 256, 0, stream>>>(xq, Wq, qb, BT, CC, CC);
    k_gemm<<<gg, 256, 0, stream>>>(xk, Wk, kb, BT, CC, CC);
    k_gemm<<<gg, 256, 0, stream>>>(xv, Wv, vb, BT, CC, CC);

    k_ln<<<BT, 256, 0, stream>>>(qb, qb, g_r, b_r);
    k_ln<<<BT, 256, 0, stream>>>(kb, kb, g_k, b_k);
    k_ln<<<BT, 256, 0, stream>>>(vb, vb, g_v, b_v);

    int rope_total = BB * TT * HH * 32;
    k_rope<<<rope_total / 256, 256, 0, stream>>>(qb, kb, cosb, sinb);

    k_attn<<<dim3(TT, HH, BB), 256, 0, stream>>>(qb, kb, vb, ob);

    k_ln<<<BT, 256, 0, stream>>>(oln, ob, g_x, b_x);
    k_gemm<<<gg, 256, 0, stream>>>(oln, Wo, out, BT, CC, CC);
}

// Round 2
// 1944.996 us; speedup vs baseline: 1.7430x; 1.7430x over previous
//
#include <hip/hip_runtime.h>
#include <math.h>

static constexpr int BB = 2;
static constexpr int TT = 1024;
static constexpr int CC = 2048;
static constexpr int HH = 32;
static constexpr int KD = 64;
static constexpr int BT = BB * TT;

// ---------------- K1: h = tanh(xxx @ w1), one block per (b,t) row ----------------
__global__ void k_lora1(const float* __restrict__ x, const float* __restrict__ shift,
                        const float* __restrict__ maa_x, const float* __restrict__ w1,
                        float* __restrict__ h_out) {
    int row = blockIdx.x;            // 0..BT-1
    int b = row / TT, t = row % TT;
    __shared__ float xs[CC];
    const float* xr = x + (size_t)row * CC;
    const float* xp = (t == 0) ? (shift + (size_t)b * CC) : (xr - CC);
    for (int c = threadIdx.x; c < CC; c += blockDim.x) {
        float xv = xr[c];
        float dx = xp[c] - xv;
        xs[c] = xv + dx * maa_x[c];
    }
    __syncthreads();
    int j = threadIdx.x;
    if (j < 96) {
        float acc = 0.f;
        for (int c = 0; c < CC; ++c) acc += xs[c] * w1[c * 96 + j];
        h_out[(size_t)row * 96 + j] = tanhf(acc);
    }
}

// ---------------- K2: xq/xk/xv = x + dx*(maa + h_l @ w2_l), block per row ----------------
__global__ void k_mix(const float* __restrict__ x, const float* __restrict__ shift,
                      const float* __restrict__ h_in, const float* __restrict__ w2,
                      const float* __restrict__ maa_r, const float* __restrict__ maa_k,
                      const float* __restrict__ maa_v,
                      float* __restrict__ oq, float* __restrict__ ok, float* __restrict__ ov) {
    int row = blockIdx.x;
    int b = row / TT, t = row % TT;
    __shared__ float hs[96];
    if (threadIdx.x < 96) hs[threadIdx.x] = h_in[(size_t)row * 96 + threadIdx.x];
    __syncthreads();
    const float* xr = x + (size_t)row * CC;
    const float* xp = (t == 0) ? (shift + (size_t)b * CC) : (xr - CC);
    for (int c = threadIdx.x; c < CC; c += blockDim.x) {
        float xv = xr[c];
        float dx = xp[c] - xv;
        float m0 = 0.f, m1 = 0.f, m2 = 0.f;
        #pragma unroll
        for (int i = 0; i < 32; ++i) {
            m0 += hs[i]      * w2[(size_t)(i)      * CC + c];
            m1 += hs[32 + i] * w2[(size_t)(32 + i) * CC + c];
            m2 += hs[64 + i] * w2[(size_t)(64 + i) * CC + c];
        }
        size_t o = (size_t)row * CC + c;
        oq[o] = xv + dx * (maa_r[c] + m0);
        ok[o] = xv + dx * (maa_k[c] + m1);
        ov[o] = xv + dx * (maa_v[c] + m2);
    }
}

// ---------------- K3: tiled f32 GEMM  Y[M,N] = A[M,K] @ W[K,N] ----------------
__global__ __launch_bounds__(256) void k_gemm(const float* __restrict__ A,
                                              const float* __restrict__ W,
                                              float* __restrict__ Y,
                                              int M, int N, int K) {
    __shared__ float As[32][65];   // [k][m] transposed, padded
    __shared__ float Bs[32][64];   // [k][n]
    int tid = threadIdx.x;
    int bm = blockIdx.y * 64, bn = blockIdx.x * 64;
    int tm = tid >> 4, tn = tid & 15;
    float acc[4][4] = {};
    for (int k0 = 0; k0 < K; k0 += 32) {
        {
            int col = tid & 31, r0 = tid >> 5;
            #pragma unroll
            for (int r = r0; r < 64; r += 8)
                As[col][r] = A[(size_t)(bm + r) * K + k0 + col];
        }
        {
            int col = tid & 63, r0 = tid >> 6;
            #pragma unroll
            for (int r = r0; r < 32; r += 4)
                Bs[r][col] = W[(size_t)(k0 + r) * N + bn + col];
        }
        __syncthreads();
        #pragma unroll
        for (int kk = 0; kk < 32; ++kk) {
            float a[4], bv[4];
            #pragma unroll
            for (int i = 0; i < 4; ++i) a[i] = As[kk][tm * 4 + i];
            #pragma unroll
            for (int j = 0; j < 4; ++j) bv[j] = Bs[kk][tn * 4 + j];
            #pragma unroll
            for (int i = 0; i < 4; ++i)
                #pragma unroll
                for (int j = 0; j < 4; ++j) acc[i][j] += a[i] * bv[j];
        }
        __syncthreads();
    }
    #pragma unroll
    for (int i = 0; i < 4; ++i)
        #pragma unroll
        for (int j = 0; j < 4; ++j)
            Y[(size_t)(bm + tm * 4 + i) * N + bn + tn * 4 + j] = acc[i][j];
}

// ---------------- K4: row LayerNorm over C ----------------
__global__ void k_ln(float* y, const float* xin, const float* g, const float* bb) {
    int row = blockIdx.x;
    const float* xr = xin + (size_t)row * CC;
    float s = 0.f, ss = 0.f;
    for (int c = threadIdx.x; c < CC; c += blockDim.x) {
        float v = xr[c]; s += v; ss += v * v;
    }
    #pragma unroll
    for (int o = 32; o > 0; o >>= 1) { s += __shfl_xor(s, o); ss += __shfl_xor(ss, o); }
    __shared__ float red[8];
    int wid = threadIdx.x >> 6;
    if ((threadIdx.x & 63) == 0) { red[wid] = s; red[wid + 4] = ss; }
    __syncthreads();
    s  = red[0] + red[1] + red[2] + red[3];
    ss = red[4] + red[5] + red[6] + red[7];
    float mu  = s * (1.0f / CC);
    float var = ss * (1.0f / CC) - mu * mu;
    float rsg = rsqrtf(var + 1e-5f);
    float* yr = y + (size_t)row * CC;
    for (int c = threadIdx.x; c < CC; c += blockDim.x)
        yr[c] = (xr[c] - mu) * rsg * g[c] + bb[c];
}

// ---------------- K5: RoPE in-place on q and k ----------------
__global__ void k_rope(float* q, float* k,
                       const float* __restrict__ cosb, const float* __restrict__ sinb) {
    int idx = blockIdx.x * blockDim.x + threadIdx.x;   // (b,t,h,d<32)
    int d = idx & 31;
    int h = (idx >> 5) & (HH - 1);
    int t = (idx >> 10) & (TT - 1);
    int b = idx >> 20;
    if (b >= BB) return;
    size_t base = ((size_t)(b * TT + t) * CC) + h * KD;
    float cv = cosb[t * 32 + d], sv = sinb[t * 32 + d];
    float q1 = q[base + d], q2 = q[base + d + 32];
    q[base + d]      = q1 * cv - q2 * sv;
    q[base + d + 32] = q1 * sv + q2 * cv;
    float k1 = k[base + d], k2 = k[base + d + 32];
    k[base + d]      = k1 * cv - k2 * sv;
    k[base + d + 32] = k1 * sv + k2 * cv;
}

// ---------------- K6: flash-style causal attention ----------------
// grid (T/64, H, B); block 256 = 16x16 threads, 4x4 micro-tile per thread.
__global__ __launch_bounds__(256) void k_fattn(const float* __restrict__ q,
                                               const float* __restrict__ k,
                                               const float* __restrict__ v,
                                               float* __restrict__ o) {
    int qt = (int)gridDim.x - 1 - (int)blockIdx.x;   // big tiles dispatched first
    int h = blockIdx.y, b = blockIdx.z;
    __shared__ float Qs[64][65];  // [d][i]  (transposed, pre-scaled)
    __shared__ float Ks[64][65];  // [d][j]  (transposed)
    __shared__ float Vs[64][65];  // [j][d]
    __shared__ float Ps[64][65];  // [j][i]  (transposed P)
    int tid = threadIdx.x;
    int lr = tid >> 2;            // load row 0..63
    int lc = (tid & 3) * 16;      // load col slice base
    int tm = tid >> 4;            // row group 0..15
    int tn = tid & 15;            // col group 0..15
    int i0 = tm * 4, c0 = tn * 4;

    size_t bh = (size_t)b * TT * CC + (size_t)h * KD;

    // stage Q tile transposed, scaled by 1/sqrt(64)
    {
        const float* qp = q + bh + (size_t)(qt * 64 + lr) * CC + lc;
        #pragma unroll
        for (int u = 0; u < 4; ++u) {
            float4 t4 = *reinterpret_cast<const float4*>(qp + u * 4);
            Qs[lc + u * 4 + 0][lr] = t4.x * 0.125f;
            Qs[lc + u * 4 + 1][lr] = t4.y * 0.125f;
            Qs[lc + u * 4 + 2][lr] = t4.z * 0.125f;
            Qs[lc + u * 4 + 3][lr] = t4.w * 0.125f;
        }
    }

    float m[4], l[4], acc[4][4];
    #pragma unroll
    for (int r = 0; r < 4; ++r) {
        m[r] = -1e30f; l[r] = 0.f;
        #pragma unroll
        for (int c = 0; c < 4; ++c) acc[r][c] = 0.f;
    }

    for (int kt = 0; kt <= qt; ++kt) {
        const float* kp = k + bh + (size_t)(kt * 64 + lr) * CC + lc;
        const float* vp = v + bh + (size_t)(kt * 64 + lr) * CC + lc;
        __syncthreads();                       // prev PV done before overwrite
        #pragma unroll
        for (int u = 0; u < 4; ++u) {
            float4 t4 = *reinterpret_cast<const float4*>(kp + u * 4);
            Ks[lc + u * 4 + 0][lr] = t4.x;
            Ks[lc + u * 4 + 1][lr] = t4.y;
            Ks[lc + u * 4 + 2][lr] = t4.z;
            Ks[lc + u * 4 + 3][lr] = t4.w;
            *reinterpret_cast<float4*>(&Vs[lr][lc + u * 4]) =
                *reinterpret_cast<const float4*>(vp + u * 4);
        }
        __syncthreads();

        // S = Q K^T micro-tile
        float s[4][4] = {};
        #pragma unroll 8
        for (int d = 0; d < 64; ++d) {
            float4 a  = *reinterpret_cast<const float4*>(&Qs[d][i0]);
            float4 bv = *reinterpret_cast<const float4*>(&Ks[d][c0]);
            s[0][0] += a.x * bv.x; s[0][1] += a.x * bv.y; s[0][2] += a.x * bv.z; s[0][3] += a.x * bv.w;
            s[1][0] += a.y * bv.x; s[1][1] += a.y * bv.y; s[1][2] += a.y * bv.z; s[1][3] += a.y * bv.w;
            s[2][0] += a.z * bv.x; s[2][1] += a.z * bv.y; s[2][2] += a.z * bv.z; s[2][3] += a.z * bv.w;
            s[3][0] += a.w * bv.x; s[3][1] += a.w * bv.y; s[3][2] += a.w * bv.z; s[3][3] += a.w * bv.w;
        }
        if (kt == qt) {   // causal mask within diagonal tile
            #pragma unroll
            for (int r = 0; r < 4; ++r)
                #pragma unroll
                for (int c = 0; c < 4; ++c)
                    if (c0 + c > i0 + r) s[r][c] = -1e30f;
        }

        // online softmax, row stats across the 16 lanes sharing the row group
        #pragma unroll
        for (int r = 0; r < 4; ++r) {
            float tmax = fmaxf(fmaxf(s[r][0], s[r][1]), fmaxf(s[r][2], s[r][3]));
            tmax = fmaxf(tmax, __shfl_xor(tmax, 1));
            tmax = fmaxf(tmax, __shfl_xor(tmax, 2));
            tmax = fmaxf(tmax, __shfl_xor(tmax, 4));
            tmax = fmaxf(tmax, __shfl_xor(tmax, 8));
            float mn = fmaxf(m[r], tmax);
            float alpha = __expf(m[r] - mn);
            float rsum = 0.f;
            #pragma unroll
            for (int c = 0; c < 4; ++c) {
                s[r][c] = __expf(s[r][c] - mn);
                rsum += s[r][c];
            }
            rsum += __shfl_xor(rsum, 1);
            rsum += __shfl_xor(rsum, 2);
            rsum += __shfl_xor(rsum, 4);
            rsum += __shfl_xor(rsum, 8);
            l[r] = l[r] * alpha + rsum;
            m[r] = mn;
            #pragma unroll
            for (int c = 0; c < 4; ++c) acc[r][c] *= alpha;
        }
        // write P transposed [j][i]
        #pragma unroll
        for (int c = 0; c < 4; ++c)
            #pragma unroll
            for (int r = 0; r < 4; ++r)
                Ps[c0 + c][i0 + r] = s[r][c];
        __syncthreads();

        // O += P V micro-tile
        #pragma unroll 8
        for (int j = 0; j < 64; ++j) {
            float4 a  = *reinterpret_cast<const float4*>(&Ps[j][i0]);
            float4 bv = *reinterpret_cast<const float4*>(&Vs[j][c0]);
            acc[0][0] += a.x * bv.x; acc[0][1] += a.x * bv.y; acc[0][2] += a.x * bv.z; acc[0][3] += a.x * bv.w;
            acc[1][0] += a.y * bv.x; acc[1][1] += a.y * bv.y; acc[1][2] += a.y * bv.z; acc[1][3] += a.y * bv.w;
            acc[2][0] += a.z * bv.x; acc[2][1] += a.z * bv.y; acc[2][2] += a.z * bv.z; acc[2][3] += a.z * bv.w;
            acc[3][0] += a.w * bv.x; acc[3][1] += a.w * bv.y; acc[3][2] += a.w * bv.z; acc[3][3] += a.w * bv.w;
        }
    }

    // epilogue: normalize and store
    #pragma unroll
    for (int r = 0; r < 4; ++r) {
        float inv = 1.0f / l[r];
        float4 t4;
        t4.x = acc[r][0] * inv; t4.y = acc[r][1] * inv;
        t4.z = acc[r][2] * inv; t4.w = acc[r][3] * inv;
        *reinterpret_cast<float4*>(o + bh + (size_t)(qt * 64 + i0 + r) * CC + c0) = t4;
    }
}

extern "C" void kernel_launch(void* const* d_in, const int* in_sizes, int n_in,
                              void* d_out, int out_size, void* d_ws, size_t ws_size,
                              hipStream_t stream) {
    const float* x     = (const float*)d_in[0];
    const float* shift = (const float*)d_in[1];
    const float* maa_x = (const float*)d_in[2];
    const float* maa_r = (const float*)d_in[3];
    const float* maa_k = (const float*)d_in[4];
    const float* maa_v = (const float*)d_in[5];
    const float* w1    = (const float*)d_in[6];
    const float* w2    = (const float*)d_in[7];
    const float* Wq    = (const float*)d_in[8];
    const float* Wk    = (const float*)d_in[9];
    const float* Wv    = (const float*)d_in[10];
    const float* Wo    = (const float*)d_in[11];
    const float* g_r   = (const float*)d_in[12];
    const float* b_r   = (const float*)d_in[13];
    const float* g_k   = (const float*)d_in[14];
    const float* b_k   = (const float*)d_in[15];
    const float* g_v   = (const float*)d_in[16];
    const float* b_v   = (const float*)d_in[17];
    const float* g_x   = (const float*)d_in[18];
    const float* b_x   = (const float*)d_in[19];
    const float* cosb  = (const float*)d_in[20];
    const float* sinb  = (const float*)d_in[21];

    float* ws = (float*)d_ws;
    const size_t NE = (size_t)BT * CC;
    float* xq  = ws;
    float* xk  = ws + NE;
    float* xv  = ws + 2 * NE;
    float* qb  = ws + 3 * NE;
    float* kb  = ws + 4 * NE;
    float* vb  = ws + 5 * NE;
    float* hb  = ws + 6 * NE;
    float* ob  = xq;                         // reuse
    float* oln = xk;                         // reuse
    float* out = (float*)d_out;

    k_lora1<<<BT, 128, 0, stream>>>(x, shift, maa_x, w1, hb);
    k_mix<<<BT, 256, 0, stream>>>(x, shift, hb, w2, maa_r, maa_k, maa_v, xq, xk, xv);

    dim3 gg(CC / 64, BT / 64);
    k_gemm<<<gg, 256, 0, stream>>>(xq, Wq, qb, BT, CC, CC);
    k_gemm<<<gg, 256, 0, stream>>>(xk, Wk, kb, BT, CC, CC);
    k_gemm<<<gg, 256, 0, stream>>>(xv, Wv, vb, BT, CC, CC);

    k_ln<<<BT, 256, 0, stream>>>(qb, qb, g_r, b_r);
    k_ln<<<BT, 256, 0, stream>>>(kb, kb, g_k, b_k);
    k_ln<<<BT, 256, 0, stream>>>(vb, vb, g_v, b_v);

    int rope_total = BB * TT * HH * 32;
    k_rope<<<rope_total / 256, 256, 0, stream>>>(qb, kb, cosb, sinb);

    k_fattn<<<dim3(TT / 64, HH, BB), 256, 0, stream>>>(qb, kb, vb, ob);

    k_ln<<<BT, 256, 0, stream>>>(oln, ob, g_x, b_x);
    k_gemm<<<gg, 256, 0, stream>>>(oln, Wo, out, BT, CC, CC);
}

// Round 3
// 636.553 us; speedup vs baseline: 5.3257x; 3.0555x over previous
//
#include <hip/hip_runtime.h>
#include <math.h>

static constexpr int BB = 2;
static constexpr int TT = 1024;
static constexpr int CC = 2048;
static constexpr int HH = 32;
static constexpr int KD = 64;
static constexpr int BT = BB * TT;

typedef short   v8s  __attribute__((ext_vector_type(8)));
typedef float   v4f  __attribute__((ext_vector_type(4)));
typedef unsigned short u16;
typedef u16     u16x8 __attribute__((ext_vector_type(8)));
typedef u16     u16x4 __attribute__((ext_vector_type(4)));
typedef float   fx4  __attribute__((ext_vector_type(4)));

__device__ __forceinline__ u16 f2bf(float f) {
    unsigned u = __builtin_bit_cast(unsigned, f);
    u = u + 0x7FFFu + ((u >> 16) & 1u);   // RNE
    return (u16)(u >> 16);
}

// ---------------- transpose-convert: W f32 [K][N] -> Wt bf16 [N][K] ----------------
__global__ __launch_bounds__(256) void k_tconv(const float* __restrict__ W,
                                               u16* __restrict__ Wt) {
    __shared__ float tile[64][65];
    int tid = threadIdx.x;
    int nb = blockIdx.x * 64, kb = blockIdx.y * 64;
    for (int i = tid; i < 4096; i += 256) {
        int r = i >> 6, c = i & 63;
        tile[r][c] = W[(size_t)(kb + r) * CC + nb + c];
    }
    __syncthreads();
    for (int i = tid; i < 4096; i += 256) {
        int r = i >> 6, c = i & 63;              // r: n-offset, c: k-offset
        Wt[(size_t)(nb + r) * CC + kb + c] = f2bf(tile[c][r]);
    }
}

// ---------------- K1: h = tanh(xxx @ w1), one block per row, 4-way K-split ----------------
__global__ __launch_bounds__(512) void k_lora1(const float* __restrict__ x,
                                               const float* __restrict__ shift,
                                               const float* __restrict__ maa_x,
                                               const float* __restrict__ w1,
                                               float* __restrict__ h_out) {
    int row = blockIdx.x;
    int b = row >> 10, t = row & (TT - 1);
    __shared__ float xs[CC];
    __shared__ float part[3][96];
    int tid = threadIdx.x;
    const float* xr = x + (size_t)row * CC;
    const float* xp = (t == 0) ? (shift + (size_t)b * CC) : (xr - CC);
    {
        int c = tid * 4;
        fx4 xv = *reinterpret_cast<const fx4*>(xr + c);
        fx4 pv = *reinterpret_cast<const fx4*>(xp + c);
        fx4 mx = *reinterpret_cast<const fx4*>(maa_x + c);
        *reinterpret_cast<fx4*>(&xs[c]) = xv + (pv - xv) * mx;
    }
    __syncthreads();
    float acc = 0.f;
    int j = tid % 96, sp = tid / 96;
    if (tid < 384) {
        int cbeg = sp * 512;
        #pragma unroll 8
        for (int c = cbeg; c < cbeg + 512; ++c)
            acc += xs[c] * w1[(size_t)c * 96 + j];
        if (sp > 0) part[sp - 1][j] = acc;
    }
    __syncthreads();
    if (tid < 96) {
        float s = acc + part[0][tid] + part[1][tid] + part[2][tid];
        h_out[(size_t)row * 96 + tid] = tanhf(s);
    }
}

// ---------------- K2: tiled mix  (64 rows x 64 cols per block) ----------------
__global__ __launch_bounds__(256) void k_mix2(const float* __restrict__ x,
                                              const float* __restrict__ shift,
                                              const float* __restrict__ h_in,
                                              const float* __restrict__ w2,
                                              const float* __restrict__ maa_r,
                                              const float* __restrict__ maa_k,
                                              const float* __restrict__ maa_v,
                                              u16* __restrict__ oq,
                                              u16* __restrict__ ok,
                                              u16* __restrict__ ov) {
    __shared__ float w2s[96][64];   // [i][c]
    __shared__ float hs[64][100];   // [r][i], padded
    int tid = threadIdx.x;
    int c0 = blockIdx.x * 64, r0 = blockIdx.y * 64;
    for (int i = tid; i < 96 * 64; i += 256) {
        int r = i >> 6, c = i & 63;
        w2s[r][c] = w2[(size_t)r * CC + c0 + c];
    }
    for (int i = tid; i < 64 * 96; i += 256) {
        int r = i / 96, jj = i - r * 96;
        hs[r][jj] = h_in[(size_t)(r0 + r) * 96 + jj];
    }
    __syncthreads();

    int cq = tid & 15, rg = tid >> 4;
    int c = c0 + cq * 4;
    fx4 acc[4][3];
    #pragma unroll
    for (int r = 0; r < 4; ++r)
        #pragma unroll
        for (int l = 0; l < 3; ++l)
            #pragma unroll
            for (int e = 0; e < 4; ++e) acc[r][l][e] = 0.f;

    #pragma unroll 2
    for (int i4 = 0; i4 < 8; ++i4) {
        fx4 hv[4][3];
        #pragma unroll
        for (int r = 0; r < 4; ++r) {
            int row = rg * 4 + r;
            hv[r][0] = *reinterpret_cast<const fx4*>(&hs[row][i4 * 4]);
            hv[r][1] = *reinterpret_cast<const fx4*>(&hs[row][32 + i4 * 4]);
            hv[r][2] = *reinterpret_cast<const fx4*>(&hs[row][64 + i4 * 4]);
        }
        #pragma unroll
        for (int e = 0; e < 4; ++e) {
            int i = i4 * 4 + e;
            fx4 w0 = *reinterpret_cast<const fx4*>(&w2s[i][cq * 4]);
            fx4 w1v = *reinterpret_cast<const fx4*>(&w2s[32 + i][cq * 4]);
            fx4 w2v = *reinterpret_cast<const fx4*>(&w2s[64 + i][cq * 4]);
            #pragma unroll
            for (int r = 0; r < 4; ++r) {
                acc[r][0] += hv[r][0][e] * w0;
                acc[r][1] += hv[r][1][e] * w1v;
                acc[r][2] += hv[r][2][e] * w2v;
            }
        }
    }

    fx4 m_r = *reinterpret_cast<const fx4*>(maa_r + c);
    fx4 m_k = *reinterpret_cast<const fx4*>(maa_k + c);
    fx4 m_v = *reinterpret_cast<const fx4*>(maa_v + c);
    #pragma unroll
    for (int r = 0; r < 4; ++r) {
        int grow = r0 + rg * 4 + r;
        int t = grow & (TT - 1), b = grow >> 10;
        const float* xr = x + (size_t)grow * CC;
        const float* xp = (t == 0) ? (shift + (size_t)b * CC) : (xr - CC);
        fx4 xv = *reinterpret_cast<const fx4*>(xr + c);
        fx4 pv = *reinterpret_cast<const fx4*>(xp + c);
        fx4 dx = pv - xv;
        fx4 rq = xv + dx * (m_r + acc[r][0]);
        fx4 rk = xv + dx * (m_k + acc[r][1]);
        fx4 rv = xv + dx * (m_v + acc[r][2]);
        u16x4 pq, pk, pvv;
        #pragma unroll
        for (int e = 0; e < 4; ++e) { pq[e] = f2bf(rq[e]); pk[e] = f2bf(rk[e]); pvv[e] = f2bf(rv[e]); }
        size_t o = (size_t)grow * CC + c;
        *reinterpret_cast<u16x4*>(oq + o) = pq;
        *reinterpret_cast<u16x4*>(ok + o) = pk;
        *reinterpret_cast<u16x4*>(ov + o) = pvv;
    }
}

// ---------------- MFMA bf16 GEMM body: C[M,N] = A[M,K] @ Bt[N,K]^T ----------------
// 128x128 tile, BK=64, 4 waves (2x2), each wave 64x64 = 4x4 frags of 16x16x32.
__device__ __forceinline__ void gemm_body(const u16* __restrict__ A,
                                          const u16* __restrict__ Bt,
                                          float* __restrict__ C,
                                          int bm, int bn) {
    constexpr int Kd = 2048, Nd = 2048;
    __shared__ u16 As[128 * 64];
    __shared__ u16 Bs[128 * 64];
    int tid = threadIdx.x;
    int lane = tid & 63, wave = tid >> 6;
    int wr = wave >> 1, wc = wave & 1;

    int srow[4], sgp[4], sdst[4];
    #pragma unroll
    for (int q = 0; q < 4; ++q) {
        int s = q * 4096 + tid * 16;         // linear byte offset in tile
        int row = s >> 7;                    // 128 B per row (64 bf16)
        int gp = (s >> 4) & 7;               // 16B granule within row
        srow[q] = row;
        sgp[q] = gp * 8;                     // element col (unswizzled)
        sdst[q] = row * 64 + ((gp ^ (row & 7)) * 8);   // swizzled LDS elem offset
    }

    v4f acc[4][4];
    #pragma unroll
    for (int i = 0; i < 4; ++i)
        #pragma unroll
        for (int j = 0; j < 4; ++j)
            #pragma unroll
            for (int e = 0; e < 4; ++e) acc[i][j][e] = 0.f;

    for (int k0 = 0; k0 < Kd; k0 += 64) {
        u16x8 ra[4], rb[4];
        #pragma unroll
        for (int q = 0; q < 4; ++q) {
            ra[q] = *reinterpret_cast<const u16x8*>(A + (size_t)(bm + srow[q]) * Kd + k0 + sgp[q]);
            rb[q] = *reinterpret_cast<const u16x8*>(Bt + (size_t)(bn + srow[q]) * Kd + k0 + sgp[q]);
        }
        __syncthreads();                     // prior MFMA LDS reads complete
        #pragma unroll
        for (int q = 0; q < 4; ++q) {
            *reinterpret_cast<u16x8*>(As + sdst[q]) = ra[q];
            *reinterpret_cast<u16x8*>(Bs + sdst[q]) = rb[q];
        }
        __syncthreads();
        #pragma unroll
        for (int ks = 0; ks < 2; ++ks) {
            int kg = ks * 4 + (lane >> 4);   // unswizzled 16B granule of fragment
            v8s af[4], bf[4];
            #pragma unroll
            for (int mi = 0; mi < 4; ++mi) {
                int rl = wr * 64 + mi * 16 + (lane & 15);
                af[mi] = *reinterpret_cast<const v8s*>(As + rl * 64 + ((kg ^ (rl & 7)) * 8));
            }
            #pragma unroll
            for (int ni = 0; ni < 4; ++ni) {
                int rl = wc * 64 + ni * 16 + (lane & 15);
                bf[ni] = *reinterpret_cast<const v8s*>(Bs + rl * 64 + ((kg ^ (rl & 7)) * 8));
            }
            #pragma unroll
            for (int mi = 0; mi < 4; ++mi)
                #pragma unroll
                for (int ni = 0; ni < 4; ++ni)
                    acc[mi][ni] = __builtin_amdgcn_mfma_f32_16x16x32_bf16(af[mi], bf[ni], acc[mi][ni], 0, 0, 0);
        }
    }

    int cr = (lane >> 4) * 4;
    int ccol = lane & 15;
    #pragma unroll
    for (int mi = 0; mi < 4; ++mi)
        #pragma unroll
        for (int ni = 0; ni < 4; ++ni) {
            float* cp = C + (size_t)(bm + wr * 64 + mi * 16 + cr) * Nd + bn + wc * 64 + ni * 16 + ccol;
            #pragma unroll
            for (int j = 0; j < 4; ++j) cp[(size_t)j * Nd] = acc[mi][ni][j];
        }
}

__global__ __launch_bounds__(256) void k_gemm_qkv(const u16* A0, const u16* A1, const u16* A2,
                                                  const u16* B0, const u16* B1, const u16* B2,
                                                  float* C0, float* C1, float* C2) {
    int z = blockIdx.z;
    const u16* A = (z == 0) ? A0 : (z == 1) ? A1 : A2;
    const u16* B = (z == 0) ? B0 : (z == 1) ? B1 : B2;
    float* C = (z == 0) ? C0 : (z == 1) ? C1 : C2;
    gemm_body(A, B, C, blockIdx.y * 128, blockIdx.x * 128);
}

__global__ __launch_bounds__(256) void k_gemm1(const u16* __restrict__ A,
                                               const u16* __restrict__ Bt,
                                               float* __restrict__ C) {
    gemm_body(A, Bt, C, blockIdx.y * 128, blockIdx.x * 128);
}

// ---------------- LayerNorm (f32 out) ----------------
__global__ void k_ln(float* y, const float* xin, const float* g, const float* bb) {
    int row = blockIdx.x;
    const float* xr = xin + (size_t)row * CC;
    float s = 0.f, ss = 0.f;
    for (int c = threadIdx.x; c < CC; c += blockDim.x) {
        float v = xr[c]; s += v; ss += v * v;
    }
    #pragma unroll
    for (int o = 32; o > 0; o >>= 1) { s += __shfl_xor(s, o); ss += __shfl_xor(ss, o); }
    __shared__ float red[8];
    int wid = threadIdx.x >> 6;
    if ((threadIdx.x & 63) == 0) { red[wid] = s; red[wid + 4] = ss; }
    __syncthreads();
    s  = red[0] + red[1] + red[2] + red[3];
    ss = red[4] + red[5] + red[6] + red[7];
    float mu  = s * (1.0f / CC);
    float var = ss * (1.0f / CC) - mu * mu;
    float rsg = rsqrtf(var + 1e-5f);
    float* yr = y + (size_t)row * CC;
    for (int c = threadIdx.x; c < CC; c += blockDim.x)
        yr[c] = (xr[c] - mu) * rsg * g[c] + bb[c];
}

// ---------------- LayerNorm (bf16 out) ----------------
__global__ void k_ln_bf(u16* y, const float* xin, const float* g, const float* bb) {
    int row = blockIdx.x;
    const float* xr = xin + (size_t)row * CC;
    float s = 0.f, ss = 0.f;
    for (int c = threadIdx.x; c < CC; c += blockDim.x) {
        float v = xr[c]; s += v; ss += v * v;
    }
    #pragma unroll
    for (int o = 32; o > 0; o >>= 1) { s += __shfl_xor(s, o); ss += __shfl_xor(ss, o); }
    __shared__ float red[8];
    int wid = threadIdx.x >> 6;
    if ((threadIdx.x & 63) == 0) { red[wid] = s; red[wid + 4] = ss; }
    __syncthreads();
    s  = red[0] + red[1] + red[2] + red[3];
    ss = red[4] + red[5] + red[6] + red[7];
    float mu  = s * (1.0f / CC);
    float var = ss * (1.0f / CC) - mu * mu;
    float rsg = rsqrtf(var + 1e-5f);
    u16* yr = y + (size_t)row * CC;
    for (int c = threadIdx.x; c < CC; c += blockDim.x)
        yr[c] = f2bf((xr[c] - mu) * rsg * g[c] + bb[c]);
}

// ---------------- RoPE in-place on q and k ----------------
__global__ void k_rope(float* q, float* k,
                       const float* __restrict__ cosb, const float* __restrict__ sinb) {
    int idx = blockIdx.x * blockDim.x + threadIdx.x;
    int d = idx & 31;
    int h = (idx >> 5) & (HH - 1);
    int t = (idx >> 10) & (TT - 1);
    int b = idx >> 20;
    if (b >= BB) return;
    size_t base = ((size_t)(b * TT + t) * CC) + h * KD;
    float cv = cosb[t * 32 + d], sv = sinb[t * 32 + d];
    float q1 = q[base + d], q2 = q[base + d + 32];
    q[base + d]      = q1 * cv - q2 * sv;
    q[base + d + 32] = q1 * sv + q2 * cv;
    float k1 = k[base + d], k2 = k[base + d + 32];
    k[base + d]      = k1 * cv - k2 * sv;
    k[base + d + 32] = k1 * sv + k2 * cv;
}

// ---------------- flash-style causal attention (f32) ----------------
__global__ __launch_bounds__(256) void k_fattn(const float* __restrict__ q,
                                               const float* __restrict__ k,
                                               const float* __restrict__ v,
                                               float* __restrict__ o) {
    int qt = (int)gridDim.x - 1 - (int)blockIdx.x;
    int h = blockIdx.y, b = blockIdx.z;
    __shared__ float Qs[64][65];
    __shared__ float Ks[64][65];
    __shared__ float Vs[64][65];
    __shared__ float Ps[64][65];
    int tid = threadIdx.x;
    int lr = tid >> 2;
    int lc = (tid & 3) * 16;
    int tm = tid >> 4;
    int tn = tid & 15;
    int i0 = tm * 4, c0 = tn * 4;

    size_t bh = (size_t)b * TT * CC + (size_t)h * KD;

    {
        const float* qp = q + bh + (size_t)(qt * 64 + lr) * CC + lc;
        #pragma unroll
        for (int u = 0; u < 4; ++u) {
            float4 t4 = *reinterpret_cast<const float4*>(qp + u * 4);
            Qs[lc + u * 4 + 0][lr] = t4.x * 0.125f;
            Qs[lc + u * 4 + 1][lr] = t4.y * 0.125f;
            Qs[lc + u * 4 + 2][lr] = t4.z * 0.125f;
            Qs[lc + u * 4 + 3][lr] = t4.w * 0.125f;
        }
    }

    float m[4], l[4], acc[4][4];
    #pragma unroll
    for (int r = 0; r < 4; ++r) {
        m[r] = -1e30f; l[r] = 0.f;
        #pragma unroll
        for (int c = 0; c < 4; ++c) acc[r][c] = 0.f;
    }

    for (int kt = 0; kt <= qt; ++kt) {
        const float* kp = k + bh + (size_t)(kt * 64 + lr) * CC + lc;
        const float* vp = v + bh + (size_t)(kt * 64 + lr) * CC + lc;
        __syncthreads();
        #pragma unroll
        for (int u = 0; u < 4; ++u) {
            float4 t4 = *reinterpret_cast<const float4*>(kp + u * 4);
            Ks[lc + u * 4 + 0][lr] = t4.x;
            Ks[lc + u * 4 + 1][lr] = t4.y;
            Ks[lc + u * 4 + 2][lr] = t4.z;
            Ks[lc + u * 4 + 3][lr] = t4.w;
            *reinterpret_cast<float4*>(&Vs[lr][lc + u * 4]) =
                *reinterpret_cast<const float4*>(vp + u * 4);
        }
        __syncthreads();

        float s[4][4] = {};
        #pragma unroll 8
        for (int d = 0; d < 64; ++d) {
            float4 a  = *reinterpret_cast<const float4*>(&Qs[d][i0]);
            float4 bv = *reinterpret_cast<const float4*>(&Ks[d][c0]);
            s[0][0] += a.x * bv.x; s[0][1] += a.x * bv.y; s[0][2] += a.x * bv.z; s[0][3] += a.x * bv.w;
            s[1][0] += a.y * bv.x; s[1][1] += a.y * bv.y; s[1][2] += a.y * bv.z; s[1][3] += a.y * bv.w;
            s[2][0] += a.z * bv.x; s[2][1] += a.z * bv.y; s[2][2] += a.z * bv.z; s[2][3] += a.z * bv.w;
            s[3][0] += a.w * bv.x; s[3][1] += a.w * bv.y; s[3][2] += a.w * bv.z; s[3][3] += a.w * bv.w;
        }
        if (kt == qt) {
            #pragma unroll
            for (int r = 0; r < 4; ++r)
                #pragma unroll
                for (int c = 0; c < 4; ++c)
                    if (c0 + c > i0 + r) s[r][c] = -1e30f;
        }

        #pragma unroll
        for (int r = 0; r < 4; ++r) {
            float tmax = fmaxf(fmaxf(s[r][0], s[r][1]), fmaxf(s[r][2], s[r][3]));
            tmax = fmaxf(tmax, __shfl_xor(tmax, 1));
            tmax = fmaxf(tmax, __shfl_xor(tmax, 2));
            tmax = fmaxf(tmax, __shfl_xor(tmax, 4));
            tmax = fmaxf(tmax, __shfl_xor(tmax, 8));
            float mn = fmaxf(m[r], tmax);
            float alpha = __expf(m[r] - mn);
            float rsum = 0.f;
            #pragma unroll
            for (int c = 0; c < 4; ++c) {
                s[r][c] = __expf(s[r][c] - mn);
                rsum += s[r][c];
            }
            rsum += __shfl_xor(rsum, 1);
            rsum += __shfl_xor(rsum, 2);
            rsum += __shfl_xor(rsum, 4);
            rsum += __shfl_xor(rsum, 8);
            l[r] = l[r] * alpha + rsum;
            m[r] = mn;
            #pragma unroll
            for (int c = 0; c < 4; ++c) acc[r][c] *= alpha;
        }
        #pragma unroll
        for (int c = 0; c < 4; ++c)
            #pragma unroll
            for (int r = 0; r < 4; ++r)
                Ps[c0 + c][i0 + r] = s[r][c];
        __syncthreads();

        #pragma unroll 8
        for (int j = 0; j < 64; ++j) {
            float4 a  = *reinterpret_cast<const float4*>(&Ps[j][i0]);
            float4 bv = *reinterpret_cast<const float4*>(&Vs[j][c0]);
            acc[0][0] += a.x * bv.x; acc[0][1] += a.x * bv.y; acc[0][2] += a.x * bv.z; acc[0][3] += a.x * bv.w;
            acc[1][0] += a.y * bv.x; acc[1][1] += a.y * bv.y; acc[1][2] += a.y * bv.z; acc[1][3] += a.y * bv.w;
            acc[2][0] += a.z * bv.x; acc[2][1] += a.z * bv.y; acc[2][2] += a.z * bv.z; acc[2][3] += a.z * bv.w;
            acc[3][0] += a.w * bv.x; acc[3][1] += a.w * bv.y; acc[3][2] += a.w * bv.z; acc[3][3] += a.w * bv.w;
        }
    }

    #pragma unroll
    for (int r = 0; r < 4; ++r) {
        float inv = 1.0f / l[r];
        float4 t4;
        t4.x = acc[r][0] * inv; t4.y = acc[r][1] * inv;
        t4.z = acc[r][2] * inv; t4.w = acc[r][3] * inv;
        *reinterpret_cast<float4*>(o + bh + (size_t)(qt * 64 + i0 + r) * CC + c0) = t4;
    }
}

extern "C" void kernel_launch(void* const* d_in, const int* in_sizes, int n_in,
                              void* d_out, int out_size, void* d_ws, size_t ws_size,
                              hipStream_t stream) {
    const float* x     = (const float*)d_in[0];
    const float* shift = (const float*)d_in[1];
    const float* maa_x = (const float*)d_in[2];
    const float* maa_r = (const float*)d_in[3];
    const float* maa_k = (const float*)d_in[4];
    const float* maa_v = (const float*)d_in[5];
    const float* w1    = (const float*)d_in[6];
    const float* w2    = (const float*)d_in[7];
    const float* Wq    = (const float*)d_in[8];
    const float* Wk    = (const float*)d_in[9];
    const float* Wv    = (const float*)d_in[10];
    const float* Wo    = (const float*)d_in[11];
    const float* g_r   = (const float*)d_in[12];
    const float* b_r   = (const float*)d_in[13];
    const float* g_k   = (const float*)d_in[14];
    const float* b_k   = (const float*)d_in[15];
    const float* g_v   = (const float*)d_in[16];
    const float* b_v   = (const float*)d_in[17];
    const float* g_x   = (const float*)d_in[18];
    const float* b_x   = (const float*)d_in[19];
    const float* cosb  = (const float*)d_in[20];
    const float* sinb  = (const float*)d_in[21];

    char* w = (char*)d_ws;
    const size_t WB = (size_t)BT * CC * 2;     // 8,388,608 B (one bf16 plane)
    u16*   wtq = (u16*)(w + 0 * WB);
    u16*   wtk = (u16*)(w + 1 * WB);
    u16*   wtv = (u16*)(w + 2 * WB);
    u16*   xqb = (u16*)(w + 3 * WB);
    u16*   xkb = (u16*)(w + 4 * WB);
    u16*   xvb = (u16*)(w + 5 * WB);
    float* qb  = (float*)(w + 6 * WB);
    float* kb  = (float*)(w + 8 * WB);
    float* vb  = (float*)(w + 10 * WB);
    float* hb  = (float*)(w + 12 * WB);        // BT*96 f32
    // phase-2 aliases (over consumed buffers):
    float* ob  = (float*)(w + 3 * WB);         // attn out over xqb+xkb
    u16*   wto = (u16*)(w + 5 * WB);           // Wo^T over xvb
    u16*   oln = (u16*)(w + 8 * WB);           // LN(attn) over kb
    float* out = (float*)d_out;

    dim3 tg(32, 32);
    k_tconv<<<tg, 256, 0, stream>>>(Wq, wtq);
    k_tconv<<<tg, 256, 0, stream>>>(Wk, wtk);
    k_tconv<<<tg, 256, 0, stream>>>(Wv, wtv);

    k_lora1<<<BT, 512, 0, stream>>>(x, shift, maa_x, w1, hb);
    k_mix2<<<dim3(32, 32), 256, 0, stream>>>(x, shift, hb, w2, maa_r, maa_k, maa_v,
                                             xqb, xkb, xvb);

    k_gemm_qkv<<<dim3(16, 16, 3), 256, 0, stream>>>(xqb, xkb, xvb, wtq, wtk, wtv,
                                                    qb, kb, vb);
    k_tconv<<<tg, 256, 0, stream>>>(Wo, wto);

    k_ln<<<BT, 256, 0, stream>>>(qb, qb, g_r, b_r);
    k_ln<<<BT, 256, 0, stream>>>(kb, kb, g_k, b_k);
    k_ln<<<BT, 256, 0, stream>>>(vb, vb, g_v, b_v);

    int rope_total = BB * TT * HH * 32;
    k_rope<<<rope_total / 256, 256, 0, stream>>>(qb, kb, cosb, sinb);

    k_fattn<<<dim3(TT / 64, HH, BB), 256, 0, stream>>>(qb, kb, vb, ob);

    k_ln_bf<<<BT, 256, 0, stream>>>(oln, ob, g_x, b_x);
    k_gemm1<<<dim3(16, 16), 256, 0, stream>>>(oln, wto, out);
}

// Round 4
// 370.649 us; speedup vs baseline: 9.1464x; 1.7174x over previous
//
#include <hip/hip_runtime.h>
#include <math.h>

static constexpr int BB = 2;
static constexpr int TT = 1024;
static constexpr int CC = 2048;
static constexpr int HH = 32;
static constexpr int KD = 64;
static constexpr int BT = BB * TT;

typedef short   v8s  __attribute__((ext_vector_type(8)));
typedef float   v4f  __attribute__((ext_vector_type(4)));
typedef unsigned short u16;
typedef u16     u16x8 __attribute__((ext_vector_type(8)));
typedef u16     u16x4 __attribute__((ext_vector_type(4)));
typedef float   fx4  __attribute__((ext_vector_type(4)));

__device__ __forceinline__ u16 f2bf(float f) {
    unsigned u = __builtin_bit_cast(unsigned, f);
    u = u + 0x7FFFu + ((u >> 16) & 1u);   // RNE
    return (u16)(u >> 16);
}

// ---------------- transpose-convert: W f32 [K][N] -> Wt bf16 [N][K] ----------------
__global__ __launch_bounds__(256) void k_tconv(const float* __restrict__ W,
                                               u16* __restrict__ Wt) {
    __shared__ float tile[64][65];
    int tid = threadIdx.x;
    int nb = blockIdx.x * 64, kb = blockIdx.y * 64;
    for (int i = tid; i < 4096; i += 256) {
        int r = i >> 6, c = i & 63;
        tile[r][c] = W[(size_t)(kb + r) * CC + nb + c];
    }
    __syncthreads();
    for (int i = tid; i < 4096; i += 256) {
        int r = i >> 6, c = i & 63;              // r: n-offset, c: k-offset
        Wt[(size_t)(nb + r) * CC + kb + c] = f2bf(tile[c][r]);
    }
}

// ---------------- K1: h = tanh(xxx @ w1) ----------------
__global__ __launch_bounds__(512) void k_lora1(const float* __restrict__ x,
                                               const float* __restrict__ shift,
                                               const float* __restrict__ maa_x,
                                               const float* __restrict__ w1,
                                               float* __restrict__ h_out) {
    int row = blockIdx.x;
    int b = row >> 10, t = row & (TT - 1);
    __shared__ float xs[CC];
    __shared__ float part[3][96];
    int tid = threadIdx.x;
    const float* xr = x + (size_t)row * CC;
    const float* xp = (t == 0) ? (shift + (size_t)b * CC) : (xr - CC);
    {
        int c = tid * 4;
        fx4 xv = *reinterpret_cast<const fx4*>(xr + c);
        fx4 pv = *reinterpret_cast<const fx4*>(xp + c);
        fx4 mx = *reinterpret_cast<const fx4*>(maa_x + c);
        *reinterpret_cast<fx4*>(&xs[c]) = xv + (pv - xv) * mx;
    }
    __syncthreads();
    float acc = 0.f;
    int j = tid % 96, sp = tid / 96;
    if (tid < 384) {
        int cbeg = sp * 512;
        #pragma unroll 8
        for (int c = cbeg; c < cbeg + 512; ++c)
            acc += xs[c] * w1[(size_t)c * 96 + j];
        if (sp > 0) part[sp - 1][j] = acc;
    }
    __syncthreads();
    if (tid < 96) {
        float s = acc + part[0][tid] + part[1][tid] + part[2][tid];
        h_out[(size_t)row * 96 + tid] = tanhf(s);
    }
}

// ---------------- K2: tiled mix ----------------
__global__ __launch_bounds__(256) void k_mix2(const float* __restrict__ x,
                                              const float* __restrict__ shift,
                                              const float* __restrict__ h_in,
                                              const float* __restrict__ w2,
                                              const float* __restrict__ maa_r,
                                              const float* __restrict__ maa_k,
                                              const float* __restrict__ maa_v,
                                              u16* __restrict__ oq,
                                              u16* __restrict__ ok,
                                              u16* __restrict__ ov) {
    __shared__ float w2s[96][64];   // [i][c]
    __shared__ float hs[64][100];   // [r][i], padded
    int tid = threadIdx.x;
    int c0 = blockIdx.x * 64, r0 = blockIdx.y * 64;
    for (int i = tid; i < 96 * 64; i += 256) {
        int r = i >> 6, c = i & 63;
        w2s[r][c] = w2[(size_t)r * CC + c0 + c];
    }
    for (int i = tid; i < 64 * 96; i += 256) {
        int r = i / 96, jj = i - r * 96;
        hs[r][jj] = h_in[(size_t)(r0 + r) * 96 + jj];
    }
    __syncthreads();

    int cq = tid & 15, rg = tid >> 4;
    int c = c0 + cq * 4;
    fx4 acc[4][3];
    #pragma unroll
    for (int r = 0; r < 4; ++r)
        #pragma unroll
        for (int l = 0; l < 3; ++l)
            #pragma unroll
            for (int e = 0; e < 4; ++e) acc[r][l][e] = 0.f;

    #pragma unroll 2
    for (int i4 = 0; i4 < 8; ++i4) {
        fx4 hv[4][3];
        #pragma unroll
        for (int r = 0; r < 4; ++r) {
            int row = rg * 4 + r;
            hv[r][0] = *reinterpret_cast<const fx4*>(&hs[row][i4 * 4]);
            hv[r][1] = *reinterpret_cast<const fx4*>(&hs[row][32 + i4 * 4]);
            hv[r][2] = *reinterpret_cast<const fx4*>(&hs[row][64 + i4 * 4]);
        }
        #pragma unroll
        for (int e = 0; e < 4; ++e) {
            int i = i4 * 4 + e;
            fx4 w0 = *reinterpret_cast<const fx4*>(&w2s[i][cq * 4]);
            fx4 w1v = *reinterpret_cast<const fx4*>(&w2s[32 + i][cq * 4]);
            fx4 w2v = *reinterpret_cast<const fx4*>(&w2s[64 + i][cq * 4]);
            #pragma unroll
            for (int r = 0; r < 4; ++r) {
                acc[r][0] += hv[r][0][e] * w0;
                acc[r][1] += hv[r][1][e] * w1v;
                acc[r][2] += hv[r][2][e] * w2v;
            }
        }
    }

    fx4 m_r = *reinterpret_cast<const fx4*>(maa_r + c);
    fx4 m_k = *reinterpret_cast<const fx4*>(maa_k + c);
    fx4 m_v = *reinterpret_cast<const fx4*>(maa_v + c);
    #pragma unroll
    for (int r = 0; r < 4; ++r) {
        int grow = r0 + rg * 4 + r;
        int t = grow & (TT - 1), b = grow >> 10;
        const float* xr = x + (size_t)grow * CC;
        const float* xp = (t == 0) ? (shift + (size_t)b * CC) : (xr - CC);
        fx4 xv = *reinterpret_cast<const fx4*>(xr + c);
        fx4 pv = *reinterpret_cast<const fx4*>(xp + c);
        fx4 dx = pv - xv;
        fx4 rq = xv + dx * (m_r + acc[r][0]);
        fx4 rk = xv + dx * (m_k + acc[r][1]);
        fx4 rv = xv + dx * (m_v + acc[r][2]);
        u16x4 pq, pk, pvv;
        #pragma unroll
        for (int e = 0; e < 4; ++e) { pq[e] = f2bf(rq[e]); pk[e] = f2bf(rk[e]); pvv[e] = f2bf(rv[e]); }
        size_t o = (size_t)grow * CC + c;
        *reinterpret_cast<u16x4*>(oq + o) = pq;
        *reinterpret_cast<u16x4*>(ok + o) = pk;
        *reinterpret_cast<u16x4*>(ov + o) = pvv;
    }
}

// ---------------- MFMA bf16 GEMM body ----------------
__device__ __forceinline__ void gemm_body(const u16* __restrict__ A,
                                          const u16* __restrict__ Bt,
                                          float* __restrict__ C,
                                          int bm, int bn) {
    constexpr int Kd = 2048, Nd = 2048;
    __shared__ u16 As[128 * 64];
    __shared__ u16 Bs[128 * 64];
    int tid = threadIdx.x;
    int lane = tid & 63, wave = tid >> 6;
    int wr = wave >> 1, wc = wave & 1;

    int srow[4], sgp[4], sdst[4];
    #pragma unroll
    for (int q = 0; q < 4; ++q) {
        int s = q * 4096 + tid * 16;
        int row = s >> 7;
        int gp = (s >> 4) & 7;
        srow[q] = row;
        sgp[q] = gp * 8;
        sdst[q] = row * 64 + ((gp ^ (row & 7)) * 8);
    }

    v4f acc[4][4];
    #pragma unroll
    for (int i = 0; i < 4; ++i)
        #pragma unroll
        for (int j = 0; j < 4; ++j)
            #pragma unroll
            for (int e = 0; e < 4; ++e) acc[i][j][e] = 0.f;

    for (int k0 = 0; k0 < Kd; k0 += 64) {
        u16x8 ra[4], rb[4];
        #pragma unroll
        for (int q = 0; q < 4; ++q) {
            ra[q] = *reinterpret_cast<const u16x8*>(A + (size_t)(bm + srow[q]) * Kd + k0 + sgp[q]);
            rb[q] = *reinterpret_cast<const u16x8*>(Bt + (size_t)(bn + srow[q]) * Kd + k0 + sgp[q]);
        }
        __syncthreads();
        #pragma unroll
        for (int q = 0; q < 4; ++q) {
            *reinterpret_cast<u16x8*>(As + sdst[q]) = ra[q];
            *reinterpret_cast<u16x8*>(Bs + sdst[q]) = rb[q];
        }
        __syncthreads();
        #pragma unroll
        for (int ks = 0; ks < 2; ++ks) {
            int kg = ks * 4 + (lane >> 4);
            v8s af[4], bf[4];
            #pragma unroll
            for (int mi = 0; mi < 4; ++mi) {
                int rl = wr * 64 + mi * 16 + (lane & 15);
                af[mi] = *reinterpret_cast<const v8s*>(As + rl * 64 + ((kg ^ (rl & 7)) * 8));
            }
            #pragma unroll
            for (int ni = 0; ni < 4; ++ni) {
                int rl = wc * 64 + ni * 16 + (lane & 15);
                bf[ni] = *reinterpret_cast<const v8s*>(Bs + rl * 64 + ((kg ^ (rl & 7)) * 8));
            }
            #pragma unroll
            for (int mi = 0; mi < 4; ++mi)
                #pragma unroll
                for (int ni = 0; ni < 4; ++ni)
                    acc[mi][ni] = __builtin_amdgcn_mfma_f32_16x16x32_bf16(af[mi], bf[ni], acc[mi][ni], 0, 0, 0);
        }
    }

    int cr = (lane >> 4) * 4;
    int ccol = lane & 15;
    #pragma unroll
    for (int mi = 0; mi < 4; ++mi)
        #pragma unroll
        for (int ni = 0; ni < 4; ++ni) {
            float* cp = C + (size_t)(bm + wr * 64 + mi * 16 + cr) * Nd + bn + wc * 64 + ni * 16 + ccol;
            #pragma unroll
            for (int j = 0; j < 4; ++j) cp[(size_t)j * Nd] = acc[mi][ni][j];
        }
}

__global__ __launch_bounds__(256) void k_gemm_qkv(const u16* A0, const u16* A1, const u16* A2,
                                                  const u16* B0, const u16* B1, const u16* B2,
                                                  float* C0, float* C1, float* C2) {
    int z = blockIdx.z;
    const u16* A = (z == 0) ? A0 : (z == 1) ? A1 : A2;
    const u16* B = (z == 0) ? B0 : (z == 1) ? B1 : B2;
    float* C = (z == 0) ? C0 : (z == 1) ? C1 : C2;
    gemm_body(A, B, C, blockIdx.y * 128, blockIdx.x * 128);
}

__global__ __launch_bounds__(256) void k_gemm1(const u16* __restrict__ A,
                                               const u16* __restrict__ Bt,
                                               float* __restrict__ C) {
    gemm_body(A, Bt, C, blockIdx.y * 128, blockIdx.x * 128);
}

// ---------------- LayerNorm (f32 out) ----------------
__global__ void k_ln(float* y, const float* xin, const float* g, const float* bb) {
    int row = blockIdx.x;
    const float* xr = xin + (size_t)row * CC;
    float s = 0.f, ss = 0.f;
    for (int c = threadIdx.x; c < CC; c += blockDim.x) {
        float v = xr[c]; s += v; ss += v * v;
    }
    #pragma unroll
    for (int o = 32; o > 0; o >>= 1) { s += __shfl_xor(s, o); ss += __shfl_xor(ss, o); }
    __shared__ float red[8];
    int wid = threadIdx.x >> 6;
    if ((threadIdx.x & 63) == 0) { red[wid] = s; red[wid + 4] = ss; }
    __syncthreads();
    s  = red[0] + red[1] + red[2] + red[3];
    ss = red[4] + red[5] + red[6] + red[7];
    float mu  = s * (1.0f / CC);
    float var = ss * (1.0f / CC) - mu * mu;
    float rsg = rsqrtf(var + 1e-5f);
    float* yr = y + (size_t)row * CC;
    for (int c = threadIdx.x; c < CC; c += blockDim.x)
        yr[c] = (xr[c] - mu) * rsg * g[c] + bb[c];
}

// ---------------- LayerNorm (bf16 out) ----------------
__global__ void k_ln_bf(u16* y, const float* xin, const float* g, const float* bb) {
    int row = blockIdx.x;
    const float* xr = xin + (size_t)row * CC;
    float s = 0.f, ss = 0.f;
    for (int c = threadIdx.x; c < CC; c += blockDim.x) {
        float v = xr[c]; s += v; ss += v * v;
    }
    #pragma unroll
    for (int o = 32; o > 0; o >>= 1) { s += __shfl_xor(s, o); ss += __shfl_xor(ss, o); }
    __shared__ float red[8];
    int wid = threadIdx.x >> 6;
    if ((threadIdx.x & 63) == 0) { red[wid] = s; red[wid + 4] = ss; }
    __syncthreads();
    s  = red[0] + red[1] + red[2] + red[3];
    ss = red[4] + red[5] + red[6] + red[7];
    float mu  = s * (1.0f / CC);
    float var = ss * (1.0f / CC) - mu * mu;
    float rsg = rsqrtf(var + 1e-5f);
    u16* yr = y + (size_t)row * CC;
    for (int c = threadIdx.x; c < CC; c += blockDim.x)
        yr[c] = f2bf((xr[c] - mu) * rsg * g[c] + bb[c]);
}

// ---------------- RoPE: f32 in -> bf16 out; q scaled by 1/8 ----------------
__global__ void k_rope_bf(const float* __restrict__ q, const float* __restrict__ k,
                          u16* __restrict__ qo, u16* __restrict__ ko,
                          const float* __restrict__ cosb, const float* __restrict__ sinb) {
    int idx = blockIdx.x * blockDim.x + threadIdx.x;
    int d = idx & 31;
    int h = (idx >> 5) & (HH - 1);
    int t = (idx >> 10) & (TT - 1);
    int b = idx >> 20;
    if (b >= BB) return;
    size_t base = ((size_t)(b * TT + t) * CC) + h * KD;
    float cv = cosb[t * 32 + d], sv = sinb[t * 32 + d];
    float q1 = q[base + d], q2 = q[base + d + 32];
    qo[base + d]      = f2bf((q1 * cv - q2 * sv) * 0.125f);
    qo[base + d + 32] = f2bf((q1 * sv + q2 * cv) * 0.125f);
    float k1 = k[base + d], k2 = k[base + d + 32];
    ko[base + d]      = f2bf(k1 * cv - k2 * sv);
    ko[base + d + 32] = f2bf(k1 * sv + k2 * cv);
}

// ---------------- MFMA bf16 flash attention ----------------
// grid (T/64, H, B), block 256 (4 waves); wave w owns Q rows [qt*64+w*16, +16).
__global__ __launch_bounds__(256) void k_mattn(const u16* __restrict__ q,
                                               const u16* __restrict__ k,
                                               const u16* __restrict__ v,
                                               float* __restrict__ o) {
    int qt = (int)gridDim.x - 1 - (int)blockIdx.x;   // big tiles first
    int h = blockIdx.y, b = blockIdx.z;
    __shared__ u16 Ks[64 * 64];       // [k-row][d], granule-swizzled
    __shared__ u16 Vt[64 * 64];       // [d][k], granule-swizzled
    __shared__ u16 Ps[4][16 * 64];    // per-wave [q][k], granule-swizzled
    int tid = threadIdx.x, lane = tid & 63, wave = tid >> 6;
    size_t bh = (size_t)b * TT * CC + (size_t)h * KD;

    // Q A-fragments, held in registers for the whole kernel
    v8s qf[2];
    {
        int qrow = qt * 64 + wave * 16 + (lane & 15);
        const u16* qp = q + bh + (size_t)qrow * CC + (lane >> 4) * 8;
        qf[0] = *reinterpret_cast<const v8s*>(qp);
        qf[1] = *reinterpret_cast<const v8s*>(qp + 32);
    }

    float mstat[4], lstat[4];
    v4f oacc[4];
    #pragma unroll
    for (int j = 0; j < 4; ++j) { mstat[j] = -1e30f; lstat[j] = 0.f; }
    #pragma unroll
    for (int nd = 0; nd < 4; ++nd)
        #pragma unroll
        for (int e = 0; e < 4; ++e) oacc[nd][e] = 0.f;

    for (int kt = 0; kt <= qt; ++kt) {
        __syncthreads();             // prior tile's LDS reads complete
        // stage K (row-major) and V (transposed), both bf16 + XOR-swizzled
        #pragma unroll
        for (int u = 0; u < 2; ++u) {
            int g = tid + u * 256;           // granule 0..511
            int r = g >> 3, gc = g & 7;      // source row, 16B-granule col
            u16x8 kvec = *reinterpret_cast<const u16x8*>(k + bh + (size_t)(kt * 64 + r) * CC + gc * 8);
            int swz = gc ^ (r & 7) ^ (r >> 3);
            *reinterpret_cast<u16x8*>(Ks + r * 64 + swz * 8) = kvec;
            u16x8 vvec = *reinterpret_cast<const u16x8*>(v + bh + (size_t)(kt * 64 + r) * CC + gc * 8);
            #pragma unroll
            for (int e = 0; e < 8; ++e) {
                int d = gc * 8 + e;
                int vswz = (r >> 3) ^ (d & 7) ^ (d >> 3);
                Vt[d * 64 + vswz * 8 + (r & 7)] = vvec[e];
            }
        }
        __syncthreads();

        // S = Q K^T  (rows: this wave's 16 q; cols: 64 k)
        v4f s[4];
        #pragma unroll
        for (int ni = 0; ni < 4; ++ni) {
            #pragma unroll
            for (int e = 0; e < 4; ++e) s[ni][e] = 0.f;
            #pragma unroll
            for (int ks = 0; ks < 2; ++ks) {
                int rl = ni * 16 + (lane & 15);
                int kg = ks * 4 + (lane >> 4);
                int swz = kg ^ (rl & 7) ^ (rl >> 3);
                v8s kf = *reinterpret_cast<const v8s*>(Ks + rl * 64 + swz * 8);
                s[ni] = __builtin_amdgcn_mfma_f32_16x16x32_bf16(qf[ks], kf, s[ni], 0, 0, 0);
            }
        }
        if (kt == qt) {   // causal mask on diagonal tile
            int qr = wave * 16 + (lane >> 4) * 4;
            int kc = lane & 15;
            #pragma unroll
            for (int ni = 0; ni < 4; ++ni)
                #pragma unroll
                for (int j = 0; j < 4; ++j)
                    if (kc + ni * 16 > qr + j) s[ni][j] = -1e30f;
        }

        // online softmax (row stats across the 16 lanes of each row group)
        float alpha[4];
        #pragma unroll
        for (int j = 0; j < 4; ++j) {
            float pm = fmaxf(fmaxf(s[0][j], s[1][j]), fmaxf(s[2][j], s[3][j]));
            pm = fmaxf(pm, __shfl_xor(pm, 1));
            pm = fmaxf(pm, __shfl_xor(pm, 2));
            pm = fmaxf(pm, __shfl_xor(pm, 4));
            pm = fmaxf(pm, __shfl_xor(pm, 8));
            float mn = fmaxf(mstat[j], pm);
            alpha[j] = __expf(mstat[j] - mn);
            float rs = 0.f;
            #pragma unroll
            for (int ni = 0; ni < 4; ++ni) {
                float p = __expf(s[ni][j] - mn);
                s[ni][j] = p;
                rs += p;
            }
            rs += __shfl_xor(rs, 1);
            rs += __shfl_xor(rs, 2);
            rs += __shfl_xor(rs, 4);
            rs += __shfl_xor(rs, 8);
            lstat[j] = lstat[j] * alpha[j] + rs;
            mstat[j] = mn;
        }
        #pragma unroll
        for (int nd = 0; nd < 4; ++nd)
            #pragma unroll
            for (int j = 0; j < 4; ++j) oacc[nd][j] *= alpha[j];

        // P -> bf16 into wave-private LDS strip (swizzled for A-frag reads)
        u16* pw = Ps[wave];
        #pragma unroll
        for (int ni = 0; ni < 4; ++ni) {
            int kc = (lane & 15) + ni * 16;
            #pragma unroll
            for (int j = 0; j < 4; ++j) {
                int qr = (lane >> 4) * 4 + j;
                int swz = (kc >> 3) ^ (qr & 7) ^ (qr >> 3);
                pw[qr * 64 + swz * 8 + (kc & 7)] = f2bf(s[ni][j]);
            }
        }
        __syncthreads();

        // O += P V
        v8s pf[2];
        #pragma unroll
        for (int ks = 0; ks < 2; ++ks) {
            int prow = lane & 15;
            int kg = ks * 4 + (lane >> 4);
            int swz = kg ^ (prow & 7) ^ (prow >> 3);
            pf[ks] = *reinterpret_cast<const v8s*>(pw + prow * 64 + swz * 8);
        }
        #pragma unroll
        for (int nd = 0; nd < 4; ++nd) {
            #pragma unroll
            for (int ks = 0; ks < 2; ++ks) {
                int vrow = nd * 16 + (lane & 15);
                int vg = ks * 4 + (lane >> 4);
                int vswz = vg ^ (vrow & 7) ^ (vrow >> 3);
                v8s vf = *reinterpret_cast<const v8s*>(Vt + vrow * 64 + vswz * 8);
                oacc[nd] = __builtin_amdgcn_mfma_f32_16x16x32_bf16(pf[ks], vf, oacc[nd], 0, 0, 0);
            }
        }
    }

    // epilogue
    #pragma unroll
    for (int j = 0; j < 4; ++j) {
        int qrow = qt * 64 + wave * 16 + (lane >> 4) * 4 + j;
        float inv = 1.0f / lstat[j];
        #pragma unroll
        for (int nd = 0; nd < 4; ++nd)
            o[bh + (size_t)qrow * CC + (lane & 15) + nd * 16] = oacc[nd][j] * inv;
    }
}

extern "C" void kernel_launch(void* const* d_in, const int* in_sizes, int n_in,
                              void* d_out, int out_size, void* d_ws, size_t ws_size,
                              hipStream_t stream) {
    const float* x     = (const float*)d_in[0];
    const float* shift = (const float*)d_in[1];
    const float* maa_x = (const float*)d_in[2];
    const float* maa_r = (const float*)d_in[3];
    const float* maa_k = (const float*)d_in[4];
    const float* maa_v = (const float*)d_in[5];
    const float* w1    = (const float*)d_in[6];
    const float* w2    = (const float*)d_in[7];
    const float* Wq    = (const float*)d_in[8];
    const float* Wk    = (const float*)d_in[9];
    const float* Wv    = (const float*)d_in[10];
    const float* Wo    = (const float*)d_in[11];
    const float* g_r   = (const float*)d_in[12];
    const float* b_r   = (const float*)d_in[13];
    const float* g_k   = (const float*)d_in[14];
    const float* b_k   = (const float*)d_in[15];
    const float* g_v   = (const float*)d_in[16];
    const float* b_v   = (const float*)d_in[17];
    const float* g_x   = (const float*)d_in[18];
    const float* b_x   = (const float*)d_in[19];
    const float* cosb  = (const float*)d_in[20];
    const float* sinb  = (const float*)d_in[21];

    char* w = (char*)d_ws;
    const size_t WB = (size_t)BT * CC * 2;     // 8 MiB bf16 plane
    u16*   wtq = (u16*)(w + 0 * WB);
    u16*   wtk = (u16*)(w + 1 * WB);
    u16*   wtv = (u16*)(w + 2 * WB);
    u16*   xqb = (u16*)(w + 3 * WB);
    u16*   xkb = (u16*)(w + 4 * WB);
    u16*   xvb = (u16*)(w + 5 * WB);
    float* qb  = (float*)(w + 6 * WB);
    float* kb  = (float*)(w + 8 * WB);
    float* vb  = (float*)(w + 10 * WB);
    float* hb  = (float*)(w + 12 * WB);
    // phase-2 aliases over consumed buffers:
    u16*   vbb = (u16*)(w + 3 * WB);           // bf16 V over xqb
    u16*   qbb = (u16*)(w + 4 * WB);           // bf16 roped Q over xkb
    u16*   kbb = (u16*)(w + 5 * WB);           // bf16 roped K over xvb
    u16*   wto = (u16*)(w + 0 * WB);           // Wo^T over wtq
    float* ob  = (float*)(w + 6 * WB);         // attn out over qb
    u16*   oln = (u16*)(w + 8 * WB);           // LN(attn) over kb
    float* out = (float*)d_out;

    dim3 tg(32, 32);
    k_tconv<<<tg, 256, 0, stream>>>(Wq, wtq);
    k_tconv<<<tg, 256, 0, stream>>>(Wk, wtk);
    k_tconv<<<tg, 256, 0, stream>>>(Wv, wtv);

    k_lora1<<<BT, 512, 0, stream>>>(x, shift, maa_x, w1, hb);
    k_mix2<<<dim3(32, 32), 256, 0, stream>>>(x, shift, hb, w2, maa_r, maa_k, maa_v,
                                             xqb, xkb, xvb);

    k_gemm_qkv<<<dim3(16, 16, 3), 256, 0, stream>>>(xqb, xkb, xvb, wtq, wtk, wtv,
                                                    qb, kb, vb);
    k_tconv<<<tg, 256, 0, stream>>>(Wo, wto);

    k_ln<<<BT, 256, 0, stream>>>(qb, qb, g_r, b_r);
    k_ln<<<BT, 256, 0, stream>>>(kb, kb, g_k, b_k);
    k_ln_bf<<<BT, 256, 0, stream>>>(vbb, vb, g_v, b_v);

    int rope_total = BB * TT * HH * 32;
    k_rope_bf<<<rope_total / 256, 256, 0, stream>>>(qb, kb, qbb, kbb, cosb, sinb);

    k_mattn<<<dim3(TT / 64, HH, BB), 256, 0, stream>>>(qbb, kbb, vbb, ob);

    k_ln_bf<<<BT, 256, 0, stream>>>(oln, ob, g_x, b_x);
    k_gemm1<<<dim3(16, 16), 256, 0, stream>>>(oln, wto, out);
}

// Round 5
// 313.156 us; speedup vs baseline: 10.8256x; 1.1836x over previous
//
#include <hip/hip_runtime.h>
#include <math.h>

static constexpr int BB = 2;
static constexpr int TT = 1024;
static constexpr int CC = 2048;
static constexpr int HH = 32;
static constexpr int KD = 64;
static constexpr int BT = BB * TT;

typedef short   v8s  __attribute__((ext_vector_type(8)));
typedef float   v4f  __attribute__((ext_vector_type(4)));
typedef unsigned short u16;
typedef u16     u16x8 __attribute__((ext_vector_type(8)));
typedef u16     u16x4 __attribute__((ext_vector_type(4)));
typedef float   fx4  __attribute__((ext_vector_type(4)));

__device__ __forceinline__ u16 f2bf(float f) {
    unsigned u = __builtin_bit_cast(unsigned, f);
    u = u + 0x7FFFu + ((u >> 16) & 1u);   // RNE
    return (u16)(u >> 16);
}

// ---------------- transpose-convert: W f32 [K][N] -> Wt bf16 [N][K] ----------------
__global__ __launch_bounds__(256) void k_tconv(const float* __restrict__ W,
                                               u16* __restrict__ Wt) {
    __shared__ float tile[64][65];
    int tid = threadIdx.x;
    int nb = blockIdx.x * 64, kb = blockIdx.y * 64;
    for (int i = tid; i < 4096; i += 256) {
        int r = i >> 6, c = i & 63;
        tile[r][c] = W[(size_t)(kb + r) * CC + nb + c];
    }
    __syncthreads();
    for (int i = tid; i < 4096; i += 256) {
        int r = i >> 6, c = i & 63;
        Wt[(size_t)(nb + r) * CC + kb + c] = f2bf(tile[c][r]);
    }
}

// fused 3-weight version (z selects)
__global__ __launch_bounds__(256) void k_tconv3(const float* __restrict__ W0,
                                                const float* __restrict__ W1,
                                                const float* __restrict__ W2,
                                                u16* __restrict__ T0,
                                                u16* __restrict__ T1,
                                                u16* __restrict__ T2) {
    const float* W = (blockIdx.z == 0) ? W0 : (blockIdx.z == 1) ? W1 : W2;
    u16* Wt = (blockIdx.z == 0) ? T0 : (blockIdx.z == 1) ? T1 : T2;
    __shared__ float tile[64][65];
    int tid = threadIdx.x;
    int nb = blockIdx.x * 64, kb = blockIdx.y * 64;
    for (int i = tid; i < 4096; i += 256) {
        int r = i >> 6, c = i & 63;
        tile[r][c] = W[(size_t)(kb + r) * CC + nb + c];
    }
    __syncthreads();
    for (int i = tid; i < 4096; i += 256) {
        int r = i >> 6, c = i & 63;
        Wt[(size_t)(nb + r) * CC + kb + c] = f2bf(tile[c][r]);
    }
}

// ---------------- K1: h = tanh(xxx @ w1) ----------------
__global__ __launch_bounds__(512) void k_lora1(const float* __restrict__ x,
                                               const float* __restrict__ shift,
                                               const float* __restrict__ maa_x,
                                               const float* __restrict__ w1,
                                               float* __restrict__ h_out) {
    int row = blockIdx.x;
    int b = row >> 10, t = row & (TT - 1);
    __shared__ float xs[CC];
    __shared__ float part[3][96];
    int tid = threadIdx.x;
    const float* xr = x + (size_t)row * CC;
    const float* xp = (t == 0) ? (shift + (size_t)b * CC) : (xr - CC);
    {
        int c = tid * 4;
        fx4 xv = *reinterpret_cast<const fx4*>(xr + c);
        fx4 pv = *reinterpret_cast<const fx4*>(xp + c);
        fx4 mx = *reinterpret_cast<const fx4*>(maa_x + c);
        *reinterpret_cast<fx4*>(&xs[c]) = xv + (pv - xv) * mx;
    }
    __syncthreads();
    float acc = 0.f;
    int j = tid % 96, sp = tid / 96;
    if (tid < 384) {
        int cbeg = sp * 512;
        #pragma unroll 8
        for (int c = cbeg; c < cbeg + 512; ++c)
            acc += xs[c] * w1[(size_t)c * 96 + j];
        if (sp > 0) part[sp - 1][j] = acc;
    }
    __syncthreads();
    if (tid < 96) {
        float s = acc + part[0][tid] + part[1][tid] + part[2][tid];
        h_out[(size_t)row * 96 + tid] = tanhf(s);
    }
}

// ---------------- K2: tiled mix ----------------
__global__ __launch_bounds__(256) void k_mix2(const float* __restrict__ x,
                                              const float* __restrict__ shift,
                                              const float* __restrict__ h_in,
                                              const float* __restrict__ w2,
                                              const float* __restrict__ maa_r,
                                              const float* __restrict__ maa_k,
                                              const float* __restrict__ maa_v,
                                              u16* __restrict__ oq,
                                              u16* __restrict__ ok,
                                              u16* __restrict__ ov) {
    __shared__ float w2s[96][64];
    __shared__ float hs[64][100];
    int tid = threadIdx.x;
    int c0 = blockIdx.x * 64, r0 = blockIdx.y * 64;
    for (int i = tid; i < 96 * 64; i += 256) {
        int r = i >> 6, c = i & 63;
        w2s[r][c] = w2[(size_t)r * CC + c0 + c];
    }
    for (int i = tid; i < 64 * 96; i += 256) {
        int r = i / 96, jj = i - r * 96;
        hs[r][jj] = h_in[(size_t)(r0 + r) * 96 + jj];
    }
    __syncthreads();

    int cq = tid & 15, rg = tid >> 4;
    int c = c0 + cq * 4;
    fx4 acc[4][3];
    #pragma unroll
    for (int r = 0; r < 4; ++r)
        #pragma unroll
        for (int l = 0; l < 3; ++l)
            #pragma unroll
            for (int e = 0; e < 4; ++e) acc[r][l][e] = 0.f;

    #pragma unroll 2
    for (int i4 = 0; i4 < 8; ++i4) {
        fx4 hv[4][3];
        #pragma unroll
        for (int r = 0; r < 4; ++r) {
            int row = rg * 4 + r;
            hv[r][0] = *reinterpret_cast<const fx4*>(&hs[row][i4 * 4]);
            hv[r][1] = *reinterpret_cast<const fx4*>(&hs[row][32 + i4 * 4]);
            hv[r][2] = *reinterpret_cast<const fx4*>(&hs[row][64 + i4 * 4]);
        }
        #pragma unroll
        for (int e = 0; e < 4; ++e) {
            int i = i4 * 4 + e;
            fx4 w0 = *reinterpret_cast<const fx4*>(&w2s[i][cq * 4]);
            fx4 w1v = *reinterpret_cast<const fx4*>(&w2s[32 + i][cq * 4]);
            fx4 w2v = *reinterpret_cast<const fx4*>(&w2s[64 + i][cq * 4]);
            #pragma unroll
            for (int r = 0; r < 4; ++r) {
                acc[r][0] += hv[r][0][e] * w0;
                acc[r][1] += hv[r][1][e] * w1v;
                acc[r][2] += hv[r][2][e] * w2v;
            }
        }
    }

    fx4 m_r = *reinterpret_cast<const fx4*>(maa_r + c);
    fx4 m_k = *reinterpret_cast<const fx4*>(maa_k + c);
    fx4 m_v = *reinterpret_cast<const fx4*>(maa_v + c);
    #pragma unroll
    for (int r = 0; r < 4; ++r) {
        int grow = r0 + rg * 4 + r;
        int t = grow & (TT - 1), b = grow >> 10;
        const float* xr = x + (size_t)grow * CC;
        const float* xp = (t == 0) ? (shift + (size_t)b * CC) : (xr - CC);
        fx4 xv = *reinterpret_cast<const fx4*>(xr + c);
        fx4 pv = *reinterpret_cast<const fx4*>(xp + c);
        fx4 dx = pv - xv;
        fx4 rq = xv + dx * (m_r + acc[r][0]);
        fx4 rk = xv + dx * (m_k + acc[r][1]);
        fx4 rv = xv + dx * (m_v + acc[r][2]);
        u16x4 pq, pk, pvv;
        #pragma unroll
        for (int e = 0; e < 4; ++e) { pq[e] = f2bf(rq[e]); pk[e] = f2bf(rk[e]); pvv[e] = f2bf(rv[e]); }
        size_t o = (size_t)grow * CC + c;
        *reinterpret_cast<u16x4*>(oq + o) = pq;
        *reinterpret_cast<u16x4*>(ok + o) = pk;
        *reinterpret_cast<u16x4*>(ov + o) = pvv;
    }
}

// ---------------- MFMA bf16 GEMM body ----------------
__device__ __forceinline__ void gemm_body(const u16* __restrict__ A,
                                          const u16* __restrict__ Bt,
                                          float* __restrict__ C,
                                          int bm, int bn) {
    constexpr int Kd = 2048, Nd = 2048;
    __shared__ u16 As[128 * 64];
    __shared__ u16 Bs[128 * 64];
    int tid = threadIdx.x;
    int lane = tid & 63, wave = tid >> 6;
    int wr = wave >> 1, wc = wave & 1;

    int srow[4], sgp[4], sdst[4];
    #pragma unroll
    for (int q = 0; q < 4; ++q) {
        int s = q * 4096 + tid * 16;
        int row = s >> 7;
        int gp = (s >> 4) & 7;
        srow[q] = row;
        sgp[q] = gp * 8;
        sdst[q] = row * 64 + ((gp ^ (row & 7)) * 8);
    }

    v4f acc[4][4];
    #pragma unroll
    for (int i = 0; i < 4; ++i)
        #pragma unroll
        for (int j = 0; j < 4; ++j)
            #pragma unroll
            for (int e = 0; e < 4; ++e) acc[i][j][e] = 0.f;

    for (int k0 = 0; k0 < Kd; k0 += 64) {
        u16x8 ra[4], rb[4];
        #pragma unroll
        for (int q = 0; q < 4; ++q) {
            ra[q] = *reinterpret_cast<const u16x8*>(A + (size_t)(bm + srow[q]) * Kd + k0 + sgp[q]);
            rb[q] = *reinterpret_cast<const u16x8*>(Bt + (size_t)(bn + srow[q]) * Kd + k0 + sgp[q]);
        }
        __syncthreads();
        #pragma unroll
        for (int q = 0; q < 4; ++q) {
            *reinterpret_cast<u16x8*>(As + sdst[q]) = ra[q];
            *reinterpret_cast<u16x8*>(Bs + sdst[q]) = rb[q];
        }
        __syncthreads();
        #pragma unroll
        for (int ks = 0; ks < 2; ++ks) {
            int kg = ks * 4 + (lane >> 4);
            v8s af[4], bf[4];
            #pragma unroll
            for (int mi = 0; mi < 4; ++mi) {
                int rl = wr * 64 + mi * 16 + (lane & 15);
                af[mi] = *reinterpret_cast<const v8s*>(As + rl * 64 + ((kg ^ (rl & 7)) * 8));
            }
            #pragma unroll
            for (int ni = 0; ni < 4; ++ni) {
                int rl = wc * 64 + ni * 16 + (lane & 15);
                bf[ni] = *reinterpret_cast<const v8s*>(Bs + rl * 64 + ((kg ^ (rl & 7)) * 8));
            }
            #pragma unroll
            for (int mi = 0; mi < 4; ++mi)
                #pragma unroll
                for (int ni = 0; ni < 4; ++ni)
                    acc[mi][ni] = __builtin_amdgcn_mfma_f32_16x16x32_bf16(af[mi], bf[ni], acc[mi][ni], 0, 0, 0);
        }
    }

    int cr = (lane >> 4) * 4;
    int ccol = lane & 15;
    #pragma unroll
    for (int mi = 0; mi < 4; ++mi)
        #pragma unroll
        for (int ni = 0; ni < 4; ++ni) {
            float* cp = C + (size_t)(bm + wr * 64 + mi * 16 + cr) * Nd + bn + wc * 64 + ni * 16 + ccol;
            #pragma unroll
            for (int j = 0; j < 4; ++j) cp[(size_t)j * Nd] = acc[mi][ni][j];
        }
}

__global__ __launch_bounds__(256) void k_gemm_qkv(const u16* A0, const u16* A1, const u16* A2,
                                                  const u16* B0, const u16* B1, const u16* B2,
                                                  float* C0, float* C1, float* C2) {
    int z = blockIdx.z;
    const u16* A = (z == 0) ? A0 : (z == 1) ? A1 : A2;
    const u16* B = (z == 0) ? B0 : (z == 1) ? B1 : B2;
    float* C = (z == 0) ? C0 : (z == 1) ? C1 : C2;
    gemm_body(A, B, C, blockIdx.y * 128, blockIdx.x * 128);
}

__global__ __launch_bounds__(256) void k_gemm1(const u16* __restrict__ A,
                                               const u16* __restrict__ Bt,
                                               float* __restrict__ C) {
    gemm_body(A, Bt, C, blockIdx.y * 128, blockIdx.x * 128);
}

// ---------------- LayerNorm (bf16 out) ----------------
__global__ void k_ln_bf(u16* y, const float* xin, const float* g, const float* bb) {
    int row = blockIdx.x;
    const float* xr = xin + (size_t)row * CC;
    float s = 0.f, ss = 0.f;
    for (int c = threadIdx.x; c < CC; c += blockDim.x) {
        float v = xr[c]; s += v; ss += v * v;
    }
    #pragma unroll
    for (int o = 32; o > 0; o >>= 1) { s += __shfl_xor(s, o); ss += __shfl_xor(ss, o); }
    __shared__ float red[8];
    int wid = threadIdx.x >> 6;
    if ((threadIdx.x & 63) == 0) { red[wid] = s; red[wid + 4] = ss; }
    __syncthreads();
    s  = red[0] + red[1] + red[2] + red[3];
    ss = red[4] + red[5] + red[6] + red[7];
    float mu  = s * (1.0f / CC);
    float var = ss * (1.0f / CC) - mu * mu;
    float rsg = rsqrtf(var + 1e-5f);
    u16* yr = y + (size_t)row * CC;
    for (int c = threadIdx.x; c < CC; c += blockDim.x)
        yr[c] = f2bf((xr[c] - mu) * rsg * g[c] + bb[c]);
}

// ---------------- fused LN(q)+LN(k)+RoPE -> bf16 (q pre-scaled 1/8) ----------------
__global__ __launch_bounds__(256) void k_lnrope(const float* __restrict__ qin,
                                                const float* __restrict__ kin,
                                                u16* __restrict__ qo, u16* __restrict__ ko,
                                                const float* __restrict__ g_r, const float* __restrict__ b_r,
                                                const float* __restrict__ g_k, const float* __restrict__ b_k,
                                                const float* __restrict__ cosb, const float* __restrict__ sinb) {
    int row = blockIdx.x;
    int t = row & (TT - 1);
    int tid = threadIdx.x;
    const float* qr_ = qin + (size_t)row * CC;
    const float* kr_ = kin + (size_t)row * CC;
    float sq = 0.f, ssq = 0.f, sk = 0.f, ssk = 0.f;
    #pragma unroll
    for (int u = 0; u < 2; ++u) {
        int c = tid * 4 + u * 1024;
        fx4 qv = *reinterpret_cast<const fx4*>(qr_ + c);
        fx4 kv = *reinterpret_cast<const fx4*>(kr_ + c);
        #pragma unroll
        for (int e = 0; e < 4; ++e) {
            sq += qv[e]; ssq += qv[e] * qv[e];
            sk += kv[e]; ssk += kv[e] * kv[e];
        }
    }
    #pragma unroll
    for (int o_ = 32; o_ > 0; o_ >>= 1) {
        sq += __shfl_xor(sq, o_); ssq += __shfl_xor(ssq, o_);
        sk += __shfl_xor(sk, o_); ssk += __shfl_xor(ssk, o_);
    }
    __shared__ float red[16];
    int wid = tid >> 6;
    if ((tid & 63) == 0) { red[wid] = sq; red[wid + 4] = ssq; red[wid + 8] = sk; red[wid + 12] = ssk; }
    __syncthreads();
    sq  = red[0] + red[1] + red[2] + red[3];
    ssq = red[4] + red[5] + red[6] + red[7];
    sk  = red[8] + red[9] + red[10] + red[11];
    ssk = red[12] + red[13] + red[14] + red[15];
    float muq = sq * (1.0f / CC), vq = ssq * (1.0f / CC) - muq * muq, rq = rsqrtf(vq + 1e-5f);
    float muk = sk * (1.0f / CC), vk = ssk * (1.0f / CC) - muk * muk, rk = rsqrtf(vk + 1e-5f);
    #pragma unroll
    for (int i = 0; i < 4; ++i) {
        int p = tid + i * 256;
        int h = p >> 5, d = p & 31;
        int c1 = h * 64 + d, c2 = c1 + 32;
        float cv = cosb[t * 32 + d], sv = sinb[t * 32 + d];
        float q1 = (qr_[c1] - muq) * rq * g_r[c1] + b_r[c1];
        float q2 = (qr_[c2] - muq) * rq * g_r[c2] + b_r[c2];
        qo[(size_t)row * CC + c1] = f2bf((q1 * cv - q2 * sv) * 0.125f);
        qo[(size_t)row * CC + c2] = f2bf((q1 * sv + q2 * cv) * 0.125f);
        float k1 = (kr_[c1] - muk) * rk * g_k[c1] + b_k[c1];
        float k2 = (kr_[c2] - muk) * rk * g_k[c2] + b_k[c2];
        ko[(size_t)row * CC + c1] = f2bf(k1 * cv - k2 * sv);
        ko[(size_t)row * CC + c2] = f2bf(k1 * sv + k2 * cv);
    }
}

// ---------------- V transpose: vbb [b*TT+t][CC] -> vtb [(b*HH+h)*KD+d][TT] ----------------
__global__ __launch_bounds__(256) void k_vtr(const u16* __restrict__ vin,
                                             u16* __restrict__ vout) {
    int t0 = blockIdx.x * 64, h = blockIdx.y, b = blockIdx.z;
    __shared__ u16 tile[64][72];
    int tid = threadIdx.x;
    #pragma unroll
    for (int u = 0; u < 2; ++u) {
        int g = tid + u * 256;
        int r = g >> 3, gc = g & 7;
        u16x8 vv = *reinterpret_cast<const u16x8*>(vin + (size_t)(b * TT + t0 + r) * CC + h * 64 + gc * 8);
        *reinterpret_cast<u16x8*>(&tile[r][gc * 8]) = vv;
    }
    __syncthreads();
    #pragma unroll
    for (int u = 0; u < 2; ++u) {
        int g = tid + u * 256;
        int d = g >> 3, tc = g & 7;
        u16x8 ov;
        #pragma unroll
        for (int e = 0; e < 8; ++e) ov[e] = tile[tc * 8 + e][d];
        *reinterpret_cast<u16x8*>(vout + ((size_t)(b * HH + h) * KD + d) * TT + t0 + tc * 8) = ov;
    }
}

// ---------------- MFMA bf16 flash attention, 128-row Q supertiles ----------------
// grid (TT/128, H, B) big-first, block 512 (8 waves); wave w owns rows st*128+w*16..+16.
__global__ __launch_bounds__(512) void k_mattn2(const u16* __restrict__ q,
                                                const u16* __restrict__ k,
                                                const u16* __restrict__ vt,
                                                float* __restrict__ o) {
    int st = (int)gridDim.x - 1 - (int)blockIdx.x;
    int h = blockIdx.y, b = blockIdx.z;
    __shared__ u16 Ks[64 * 64];
    __shared__ u16 Vs[64 * 64];
    __shared__ u16 Ps[8][16 * 64];
    int tid = threadIdx.x, lane = tid & 63, wave = tid >> 6;
    size_t bh = (size_t)b * TT * CC + (size_t)h * KD;
    const u16* vth = vt + (size_t)(b * HH + h) * KD * TT;
    int qrow0 = st * 128 + wave * 16;

    v8s qf[2];
    {
        const u16* qp = q + bh + (size_t)(qrow0 + (lane & 15)) * CC + (lane >> 4) * 8;
        qf[0] = *reinterpret_cast<const v8s*>(qp);
        qf[1] = *reinterpret_cast<const v8s*>(qp + 32);
    }

    float mstat[4], lstat[4];
    v4f oacc[4];
    #pragma unroll
    for (int j = 0; j < 4; ++j) { mstat[j] = -1e30f; lstat[j] = 0.f; }
    #pragma unroll
    for (int nd = 0; nd < 4; ++nd)
        #pragma unroll
        for (int e = 0; e < 4; ++e) oacc[nd][e] = 0.f;

    int sr = tid >> 3, sgc = tid & 7;           // staging: row 0..63, granule 0..7
    int sswz = sgc ^ (sr & 7) ^ (sr >> 3);
    u16* pw = Ps[wave];
    int ktmax = 2 * st + 1;

    for (int kt = 0; kt <= ktmax; ++kt) {
        __syncthreads();                         // prior tile LDS reads done
        {
            u16x8 kv = *reinterpret_cast<const u16x8*>(k + bh + (size_t)(kt * 64 + sr) * CC + sgc * 8);
            *reinterpret_cast<u16x8*>(Ks + sr * 64 + sswz * 8) = kv;
            u16x8 vv = *reinterpret_cast<const u16x8*>(vth + (size_t)sr * TT + kt * 64 + sgc * 8);
            *reinterpret_cast<u16x8*>(Vs + sr * 64 + sswz * 8) = vv;
        }
        __syncthreads();
        if (kt * 64 > qrow0 + 15) continue;      // fully masked for this wave

        // S = Q K^T
        v4f s[4];
        #pragma unroll
        for (int ni = 0; ni < 4; ++ni) {
            #pragma unroll
            for (int e = 0; e < 4; ++e) s[ni][e] = 0.f;
            #pragma unroll
            for (int ks = 0; ks < 2; ++ks) {
                int rl = ni * 16 + (lane & 15);
                int kg = ks * 4 + (lane >> 4);
                int swz = kg ^ (rl & 7) ^ (rl >> 3);
                v8s kf = *reinterpret_cast<const v8s*>(Ks + rl * 64 + swz * 8);
                s[ni] = __builtin_amdgcn_mfma_f32_16x16x32_bf16(qf[ks], kf, s[ni], 0, 0, 0);
            }
        }
        if (kt * 64 + 63 > qrow0) {              // diagonal overlap: causal mask
            int qr = qrow0 + (lane >> 4) * 4;
            int kc = kt * 64 + (lane & 15);
            #pragma unroll
            for (int ni = 0; ni < 4; ++ni)
                #pragma unroll
                for (int j = 0; j < 4; ++j)
                    if (kc + ni * 16 > qr + j) s[ni][j] = -1e30f;
        }

        // online softmax
        float alpha[4];
        #pragma unroll
        for (int j = 0; j < 4; ++j) {
            float pm = fmaxf(fmaxf(s[0][j], s[1][j]), fmaxf(s[2][j], s[3][j]));
            pm = fmaxf(pm, __shfl_xor(pm, 1));
            pm = fmaxf(pm, __shfl_xor(pm, 2));
            pm = fmaxf(pm, __shfl_xor(pm, 4));
            pm = fmaxf(pm, __shfl_xor(pm, 8));
            float mn = fmaxf(mstat[j], pm);
            alpha[j] = __expf(mstat[j] - mn);
            float rs = 0.f;
            #pragma unroll
            for (int ni = 0; ni < 4; ++ni) {
                float p = __expf(s[ni][j] - mn);
                s[ni][j] = p;
                rs += p;
            }
            rs += __shfl_xor(rs, 1);
            rs += __shfl_xor(rs, 2);
            rs += __shfl_xor(rs, 4);
            rs += __shfl_xor(rs, 8);
            lstat[j] = lstat[j] * alpha[j] + rs;
            mstat[j] = mn;
        }
        #pragma unroll
        for (int nd = 0; nd < 4; ++nd)
            #pragma unroll
            for (int j = 0; j < 4; ++j) oacc[nd][j] *= alpha[j];

        // P -> bf16 into wave-private strip (no barrier needed: wave-local RAW)
        #pragma unroll
        for (int ni = 0; ni < 4; ++ni) {
            int kc = (lane & 15) + ni * 16;
            #pragma unroll
            for (int j = 0; j < 4; ++j) {
                int qr = (lane >> 4) * 4 + j;
                int swz = (kc >> 3) ^ (qr & 7) ^ (qr >> 3);
                pw[qr * 64 + swz * 8 + (kc & 7)] = f2bf(s[ni][j]);
            }
        }

        // O += P V
        v8s pf[2];
        #pragma unroll
        for (int ks = 0; ks < 2; ++ks) {
            int prow = lane & 15;
            int kg = ks * 4 + (lane >> 4);
            int swz = kg ^ (prow & 7) ^ (prow >> 3);
            pf[ks] = *reinterpret_cast<const v8s*>(pw + prow * 64 + swz * 8);
        }
        #pragma unroll
        for (int nd = 0; nd < 4; ++nd) {
            #pragma unroll
            for (int ks = 0; ks < 2; ++ks) {
                int vrow = nd * 16 + (lane & 15);
                int vg = ks * 4 + (lane >> 4);
                int vswz = vg ^ (vrow & 7) ^ (vrow >> 3);
                v8s vf = *reinterpret_cast<const v8s*>(Vs + vrow * 64 + vswz * 8);
                oacc[nd] = __builtin_amdgcn_mfma_f32_16x16x32_bf16(pf[ks], vf, oacc[nd], 0, 0, 0);
            }
        }
    }

    #pragma unroll
    for (int j = 0; j < 4; ++j) {
        int qrow = qrow0 + (lane >> 4) * 4 + j;
        float inv = 1.0f / lstat[j];
        #pragma unroll
        for (int nd = 0; nd < 4; ++nd)
            o[bh + (size_t)qrow * CC + (lane & 15) + nd * 16] = oacc[nd][j] * inv;
    }
}

extern "C" void kernel_launch(void* const* d_in, const int* in_sizes, int n_in,
                              void* d_out, int out_size, void* d_ws, size_t ws_size,
                              hipStream_t stream) {
    const float* x     = (const float*)d_in[0];
    const float* shift = (const float*)d_in[1];
    const float* maa_x = (const float*)d_in[2];
    const float* maa_r = (const float*)d_in[3];
    const float* maa_k = (const float*)d_in[4];
    const float* maa_v = (const float*)d_in[5];
    const float* w1    = (const float*)d_in[6];
    const float* w2    = (const float*)d_in[7];
    const float* Wq    = (const float*)d_in[8];
    const float* Wk    = (const float*)d_in[9];
    const float* Wv    = (const float*)d_in[10];
    const float* Wo    = (const float*)d_in[11];
    const float* g_r   = (const float*)d_in[12];
    const float* b_r   = (const float*)d_in[13];
    const float* g_k   = (const float*)d_in[14];
    const float* b_k   = (const float*)d_in[15];
    const float* g_v   = (const float*)d_in[16];
    const float* b_v   = (const float*)d_in[17];
    const float* g_x   = (const float*)d_in[18];
    const float* b_x   = (const float*)d_in[19];
    const float* cosb  = (const float*)d_in[20];
    const float* sinb  = (const float*)d_in[21];

    char* w = (char*)d_ws;
    const size_t WB = (size_t)BT * CC * 2;     // 8 MiB bf16 plane
    u16*   wtq = (u16*)(w + 0 * WB);
    u16*   wtk = (u16*)(w + 1 * WB);
    u16*   wtv = (u16*)(w + 2 * WB);
    u16*   xqb = (u16*)(w + 3 * WB);
    u16*   xkb = (u16*)(w + 4 * WB);
    u16*   xvb = (u16*)(w + 5 * WB);
    float* qb  = (float*)(w + 6 * WB);         // planes 6-7
    float* kb  = (float*)(w + 8 * WB);         // planes 8-9
    float* vb  = (float*)(w + 10 * WB);        // planes 10-11
    float* hb  = (float*)(w + 12 * WB);        // BT*96 f32
    // phase-2 aliases over consumed planes:
    u16*   qbb = (u16*)(w + 3 * WB);           // roped Q over xqb
    u16*   kbb = (u16*)(w + 4 * WB);           // roped K over xkb
    u16*   vbb = (u16*)(w + 5 * WB);           // LN'd V over xvb
    u16*   vtb = (u16*)(w + 8 * WB);           // V^T over kb (consumed)
    u16*   wto = (u16*)(w + 0 * WB);           // Wo^T over wtq (consumed)
    float* ob  = (float*)(w + 6 * WB);         // attn out over qb (consumed)
    u16*   oln = (u16*)(w + 10 * WB);          // LN(attn) over vb (consumed)
    float* out = (float*)d_out;

    k_tconv3<<<dim3(32, 32, 3), 256, 0, stream>>>(Wq, Wk, Wv, wtq, wtk, wtv);

    k_lora1<<<BT, 512, 0, stream>>>(x, shift, maa_x, w1, hb);
    k_mix2<<<dim3(32, 32), 256, 0, stream>>>(x, shift, hb, w2, maa_r, maa_k, maa_v,
                                             xqb, xkb, xvb);

    k_gemm_qkv<<<dim3(16, 16, 3), 256, 0, stream>>>(xqb, xkb, xvb, wtq, wtk, wtv,
                                                    qb, kb, vb);
    k_tconv<<<dim3(32, 32), 256, 0, stream>>>(Wo, wto);

    k_lnrope<<<BT, 256, 0, stream>>>(qb, kb, qbb, kbb, g_r, b_r, g_k, b_k, cosb, sinb);
    k_ln_bf<<<BT, 256, 0, stream>>>(vbb, vb, g_v, b_v);
    k_vtr<<<dim3(TT / 64, HH, BB), 256, 0, stream>>>(vbb, vtb);

    k_mattn2<<<dim3(TT / 128, HH, BB), 512, 0, stream>>>(qbb, kbb, vtb, ob);

    k_ln_bf<<<BT, 256, 0, stream>>>(oln, ob, g_x, b_x);
    k_gemm1<<<dim3(16, 16), 256, 0, stream>>>(oln, wto, out);
}